// Round 11
// baseline (585.736 us; speedup 1.0000x reference)
//
#include <hip/hip_runtime.h>
#include <math.h>

typedef unsigned short u16;
typedef signed char i8;
typedef short s8v __attribute__((ext_vector_type(8)));   // 8 bf16
typedef float f4v __attribute__((ext_vector_type(4)));
typedef int   i4v __attribute__((ext_vector_type(4)));   // 16 i8 / 4 i32 acc

constexpr int Bv = 8, Tv = 2048, Cv = 768, Hv = 3072;
constexpr int BT = Bv * Tv;       // 16384 tokens
constexpr int BC = Bv * Cv;       // 6144 channels
constexpr int Lc = 32;            // WKV chunk length
constexpr int NCHK = Tv / Lc;     // 64 chunks
constexpr int SI = Lc / 16;       // 2 sub-chunks
constexpr int KVS = 2304;         // fused k|v|sr row stride

__device__ __forceinline__ float b2f(u16 x) { return __uint_as_float(((unsigned)x) << 16); }
__device__ __forceinline__ u16 f2b(float f) {
    unsigned u = __float_as_uint(f);
    return (u16)((u + 0x7fffu + ((u >> 16) & 1u)) >> 16);   // RNE
}

#define GLOAD_LDS(g, l) __builtin_amdgcn_global_load_lds( \
    (const __attribute__((address_space(1))) void*)(g),    \
    (__attribute__((address_space(3))) void*)(l), 16, 0, 0)
#define BAR()  __builtin_amdgcn_s_barrier()
#define VM4()  asm volatile("s_waitcnt vmcnt(4)" ::: "memory")
#define VM8()  asm volatile("s_waitcnt vmcnt(8)" ::: "memory")
#define VM0()  asm volatile("s_waitcnt vmcnt(0)" ::: "memory")

// ---------------- LayerNorm fp32 -> per-row int8 + scale ----------------
__global__ __launch_bounds__(256) void ln_q8(const float* __restrict__ x,
    const float* __restrict__ w, const float* __restrict__ b,
    i8* __restrict__ outq, float* __restrict__ sA)
{
    __shared__ float sh[8];
    int row = blockIdx.x;
    const float* xr = x + (size_t)row * Cv;
    float vals[3];
    float s = 0.f, s2 = 0.f;
#pragma unroll
    for (int i = 0; i < 3; i++) {
        float t = xr[threadIdx.x + 256 * i];
        vals[i] = t; s += t; s2 += t * t;
    }
#pragma unroll
    for (int off = 32; off > 0; off >>= 1) {
        s  += __shfl_down(s, off);
        s2 += __shfl_down(s2, off);
    }
    int wid = threadIdx.x >> 6;
    if ((threadIdx.x & 63) == 0) { sh[wid] = s; sh[4 + wid] = s2; }
    __syncthreads();
    if (threadIdx.x == 0) {
        sh[0] = sh[0] + sh[1] + sh[2] + sh[3];
        sh[4] = sh[4] + sh[5] + sh[6] + sh[7];
    }
    __syncthreads();
    float mean = sh[0] * (1.f / Cv);
    float var  = sh[4] * (1.f / Cv) - mean * mean;
    float rstd = rsqrtf(var + 1e-5f);
    float nv[3], am = 0.f;
#pragma unroll
    for (int i = 0; i < 3; i++) {
        int j = threadIdx.x + 256 * i;
        nv[i] = (vals[i] - mean) * rstd * w[j] + b[j];
        am = fmaxf(am, fabsf(nv[i]));
    }
#pragma unroll
    for (int off = 32; off > 0; off >>= 1) am = fmaxf(am, __shfl_xor(am, off));
    __syncthreads();
    if ((threadIdx.x & 63) == 0) sh[wid] = am;
    __syncthreads();
    am = fmaxf(fmaxf(sh[0], sh[1]), fmaxf(sh[2], sh[3]));
    am = fmaxf(am, 1e-20f);
    float inv = 127.f / am;
    if (threadIdx.x == 0) sA[row] = am * (1.f / 127.f);
    i8* orow = outq + (size_t)row * Cv;
#pragma unroll
    for (int i = 0; i < 3; i++)
        orow[threadIdx.x + 256 * i] = (i8)(int)rintf(nv[i] * inv);
}

// ---------------- all six K=768 weights -> one stacked i8 buffer ----------------
__global__ __launch_bounds__(256) void quant_w6(const float* __restrict__ wk,
    const float* __restrict__ wv, const float* __restrict__ wr,
    const float* __restrict__ wo, const float* __restrict__ wkf,
    const float* __restrict__ wrf, i8* __restrict__ dst, float* __restrict__ sW)
{
    __shared__ float sh[4];
    int row = blockIdx.x;
    const float* src;
    if      (row < 768)  src = wk  + (size_t)row * Cv;
    else if (row < 1536) src = wv  + (size_t)(row - 768) * Cv;
    else if (row < 2304) src = wr  + (size_t)(row - 1536) * Cv;
    else if (row < 3072) src = wo  + (size_t)(row - 2304) * Cv;
    else if (row < 6144) src = wkf + (size_t)(row - 3072) * Cv;
    else                 src = wrf + (size_t)(row - 6144) * Cv;
    i8* dr = dst + (size_t)row * Cv;
    float am = 0.f;
    for (int j = threadIdx.x; j < Cv; j += 256) am = fmaxf(am, fabsf(src[j]));
#pragma unroll
    for (int off = 32; off > 0; off >>= 1) am = fmaxf(am, __shfl_xor(am, off));
    int wid = threadIdx.x >> 6;
    if ((threadIdx.x & 63) == 0) sh[wid] = am;
    __syncthreads();
    am = fmaxf(fmaxf(sh[0], sh[1]), fmaxf(sh[2], sh[3]));
    am = fmaxf(am, 1e-20f);
    float inv = 127.f / am;
    if (threadIdx.x == 0) sW[row] = am * (1.f / 127.f);
    for (int j = threadIdx.x; j < Cv; j += 256) dr[j] = (i8)(int)rintf(src[j] * inv);
}

// ---------------- single fp32 weight (K=3072) -> i8 ----------------
__global__ __launch_bounds__(256) void quant_w1(const float* __restrict__ src0,
    i8* __restrict__ dst, float* __restrict__ sW, int K)
{
    __shared__ float sh[4];
    int row = blockIdx.x;
    const float* src = src0 + (size_t)row * K;
    i8* dr = dst + (size_t)row * K;
    float am = 0.f;
    for (int j = threadIdx.x; j < K; j += 256) am = fmaxf(am, fabsf(src[j]));
#pragma unroll
    for (int off = 32; off > 0; off >>= 1) am = fmaxf(am, __shfl_xor(am, off));
    int wid = threadIdx.x >> 6;
    if ((threadIdx.x & 63) == 0) sh[wid] = am;
    __syncthreads();
    am = fmaxf(fmaxf(sh[0], sh[1]), fmaxf(sh[2], sh[3]));
    am = fmaxf(am, 1e-20f);
    float inv = 127.f / am;
    if (threadIdx.x == 0) sW[row] = am * (1.f / 127.f);
    for (int j = threadIdx.x; j < K; j += 256) dr[j] = (i8)(int)rintf(src[j] * inv);
}

// ---------------- per-row bf16 -> i8 (kf), vectorized ----------------
__global__ __launch_bounds__(256) void quant_bf(const u16* __restrict__ src,
    i8* __restrict__ dst, float* __restrict__ sA, int K)
{
    __shared__ float sh[4];
    int row = blockIdx.x;
    const u16* sr_ = src + (size_t)row * K;
    i8* dr = dst + (size_t)row * K;
    float am = 0.f;
    for (int j = threadIdx.x * 8; j < K; j += 2048) {
        s8v v = *(const s8v*)(sr_ + j);
#pragma unroll
        for (int b = 0; b < 8; b++) am = fmaxf(am, fabsf(b2f((u16)v[b])));
    }
#pragma unroll
    for (int off = 32; off > 0; off >>= 1) am = fmaxf(am, __shfl_xor(am, off));
    int wid = threadIdx.x >> 6;
    if ((threadIdx.x & 63) == 0) sh[wid] = am;
    __syncthreads();
    am = fmaxf(fmaxf(sh[0], sh[1]), fmaxf(sh[2], sh[3]));
    am = fmaxf(am, 1e-20f);
    float inv = 127.f / am;
    if (threadIdx.x == 0) sA[row] = am * (1.f / 127.f);
    for (int j = threadIdx.x * 8; j < K; j += 2048) {
        s8v v = *(const s8v*)(sr_ + j);
        unsigned lo = 0, hi = 0;
#pragma unroll
        for (int b = 0; b < 4; b++) {
            lo |= ((unsigned)(unsigned char)(i8)(int)rintf(b2f((u16)v[b]) * inv)) << (8 * b);
            hi |= ((unsigned)(unsigned char)(i8)(int)rintf(b2f((u16)v[4 + b]) * inv)) << (8 * b);
        }
        uint2 o2; o2.x = lo; o2.y = hi;
        *(uint2*)(dr + j) = o2;
    }
}

// ---------------- y' (bf16, stride KVS) -> per-row i8 + scale ----------------
__global__ __launch_bounds__(256) void quant_y(const u16* __restrict__ kvs,
    i8* __restrict__ y8, float* __restrict__ sY)
{
    __shared__ float sh[4];
    int row = blockIdx.x;
    const u16* yr = kvs + (size_t)row * KVS;
    float v[3], am = 0.f;
#pragma unroll
    for (int i = 0; i < 3; i++) {
        v[i] = b2f(yr[threadIdx.x + 256 * i]);
        am = fmaxf(am, fabsf(v[i]));
    }
#pragma unroll
    for (int off = 32; off > 0; off >>= 1) am = fmaxf(am, __shfl_xor(am, off));
    int wid = threadIdx.x >> 6;
    if ((threadIdx.x & 63) == 0) sh[wid] = am;
    __syncthreads();
    am = fmaxf(fmaxf(sh[0], sh[1]), fmaxf(sh[2], sh[3]));
    am = fmaxf(am, 1e-20f);
    float inv = 127.f / am;
    if (threadIdx.x == 0) sY[row] = am * (1.f / 127.f);
    i8* orow = y8 + (size_t)row * Cv;
#pragma unroll
    for (int i = 0; i < 3; i++)
        orow[threadIdx.x + 256 * i] = (i8)(int)rintf(v[i] * inv);
}

// ---------------- int8 MFMA GEMM, 256x256 / 8x8-per-wave, 1 block/CU ----------------
// BM=BN=256, BK=64, 256 thr = 4 waves (2x2); per-wave C = 128x128 (8x8 frags),
// mfma_i32_16x16x64_i8. LDS: 3 bufs x {A,B} x [256 x 64 i8] = 96 KiB -> 1 blk/CU.
// Reuse ratio 0.25 ds_read/MFMA (vs 0.5 at 4x4): per phase-CU LDS = 64KB rd + 32KB wr
// = ~857 cyc < MFMA 1300 cyc -> MFMA-bound (round-10 was LDS-BW-bound at 1300).
// Per phase: 16 ds_read | stage tile t+2 (8 gload_lds) | 64 MFMA | vmcnt(8) | BAR.
// 3-buf race-free per round-10 argument. Swizzle slot^=(row>>1)&3 (same formulas;
// row-algebra identical since all bases are multiples of 32).
// Grid 1-D nb=(M/256)*ny, nb%8==0, XCD-chunk + y-fast decode. K%128==0.
// EPI 0: bf16 out, sigmoid col>=sigoff | 4: f32 e0+r | 5: dual kf/gate
template<int EPI>
__global__ __launch_bounds__(256, 1) void gemm256q(const i8* __restrict__ A,
    const i8* __restrict__ W, void* __restrict__ outv, void* __restrict__ out2,
    int K, int lda, int ldw, int ldc, int ldc2, int ny, int sigoff,
    const float* __restrict__ sA, const float* __restrict__ sW,
    const float* __restrict__ e0)
{
    __shared__ i8 lds[3][2][16384];            // [buf][A/B][256*64]
    const int tid = threadIdx.x;
    const int wv = tid >> 6, l = tid & 63;
    const int nb = (int)gridDim.x, bid = (int)blockIdx.x;
    const int q = nb >> 3;
    const int sw = (bid & 7) * q + (bid >> 3);
    const int bm = (sw / ny) * 256, bn = (sw % ny) * 256;
    const int wr = wv >> 1, wc = wv & 1;
    // staging: wave covers 64 rows (row0..row0+48 by 16), 4 x 16B chunks per row
    const int row0 = wv * 64 + (l >> 2);
    const int scol = ((l & 3) ^ ((l >> 3) & 3)) << 4;        // swizzled 16B slot (i8)
    const i8* srcA = A + (size_t)(bm + row0) * lda + scol;
    const i8* srcB = W + (size_t)(bn + row0) * ldw + scol;
#define STG(buf, kt) { \
    const size_t kc = (size_t)(kt) * 64; \
    GLOAD_LDS(srcA + kc,                    &lds[buf][0][wv * 4096]); \
    GLOAD_LDS(srcA + kc + (size_t)16 * lda, &lds[buf][0][wv * 4096 + 1024]); \
    GLOAD_LDS(srcA + kc + (size_t)32 * lda, &lds[buf][0][wv * 4096 + 2048]); \
    GLOAD_LDS(srcA + kc + (size_t)48 * lda, &lds[buf][0][wv * 4096 + 3072]); \
    GLOAD_LDS(srcB + kc,                    &lds[buf][1][wv * 4096]); \
    GLOAD_LDS(srcB + kc + (size_t)16 * ldw, &lds[buf][1][wv * 4096 + 1024]); \
    GLOAD_LDS(srcB + kc + (size_t)32 * ldw, &lds[buf][1][wv * 4096 + 2048]); \
    GLOAD_LDS(srcB + kc + (size_t)48 * ldw, &lds[buf][1][wv * 4096 + 3072]); }
    // fragment reads: row = (l&15) + 16*frag, k-slot (l>>4), swizzled
    const int swz = ((l >> 4) ^ ((l >> 1) & 3)) << 4;
    const int ab  = (wr * 128 + (l & 15)) * 64 + swz;
    const int bb  = (wc * 128 + (l & 15)) * 64 + swz;
#define RD(pbuf) { \
    _Pragma("unroll") \
    for (int i = 0; i < 8; i++) { \
        a4[i] = *(const i4v*)&lds[pbuf][0][ab + i * 1024]; \
        b4[i] = *(const i4v*)&lds[pbuf][1][bb + i * 1024]; } }
#define MF() { \
    __builtin_amdgcn_s_setprio(1); \
    _Pragma("unroll") \
    for (int mm = 0; mm < 8; mm++) \
        _Pragma("unroll") \
        for (int nn = 0; nn < 8; nn++) \
            acc[mm][nn] = __builtin_amdgcn_mfma_i32_16x16x64_i8( \
                a4[mm], b4[nn], acc[mm][nn], 0, 0, 0); \
    __builtin_amdgcn_s_setprio(0); }

    i4v acc[8][8] = {};
    const int NKT = K >> 6;
    STG(0, 0); STG(1, 1);
    VM8();                                     // tile 0's 8 loads landed
    BAR();
    int cur = 0;
    for (int t = 0; t < NKT; ++t) {
        i4v a4[8], b4[8];
        RD(cur);
        const int n2 = cur >= 1 ? cur - 1 : 2;             // (cur+2)%3
        if (t + 2 < NKT) STG(n2, t + 2);
        MF();
        if (t + 2 < NKT)      VM8();           // tile t+1 landed (issued 1 phase ago)
        else if (t + 1 < NKT) VM0();
        BAR();
        cur = cur >= 2 ? 0 : cur + 1;
    }
#undef STG
#undef RD
#undef MF
    // epilogue: C row=(lane>>4)*4+i, col=lane&15 per 16x16 fragment
    const int r0 = bm + wr * 128 + ((l >> 4) << 2);
    const int c0 = bn + wc * 128 + (l & 15);
    float sw8[8];
#pragma unroll
    for (int nf = 0; nf < 8; nf++) sw8[nf] = sW[c0 + nf * 16];
#pragma unroll
    for (int mf = 0; mf < 8; mf++)
#pragma unroll
        for (int i = 0; i < 4; i++) {
            const int row = r0 + mf * 16 + i;
            const float sar = sA[row];
#pragma unroll
            for (int nf = 0; nf < 8; nf++) {
                const int col = c0 + nf * 16;
                float r = (float)acc[mf][nf][i] * sar * sw8[nf];
                if (EPI == 0) {
                    if (col >= sigoff) r = 1.f / (1.f + __expf(-r));
                    ((u16*)outv)[(size_t)row * ldc + col] = f2b(r);
                } else if (EPI == 4) {
                    size_t o = (size_t)row * ldc + col;
                    ((float*)outv)[o] = e0[o] + r;
                } else if (EPI == 5) {
                    if (col < sigoff) {
                        float t2 = fmaxf(r, 0.f);
                        ((u16*)outv)[(size_t)row * ldc + col] = f2b(t2 * t2);
                    } else {
                        float sg = 1.f / (1.f + __expf(-r));
                        ((u16*)out2)[(size_t)row * ldc2 + (col - sigoff)] = f2b(sg);
                    }
                }
            }
        }
}

// ---------------- int8 MFMA GEMM, 128x128 / 3 blocks/CU (round-10 proven; FFN down) --
template<int EPI>
__global__ __launch_bounds__(256, 3) void gemm128q(const i8* __restrict__ A,
    const i8* __restrict__ W, void* __restrict__ outv,
    int K, int lda, int ldw, int ldc, int ny,
    const float* __restrict__ sA, const float* __restrict__ sW,
    const float* __restrict__ e0, const u16* __restrict__ e1)
{
    __shared__ i8 lds[3][2][8192];             // [buf][A/B][128*64]
    const int tid = threadIdx.x;
    const int wv = tid >> 6, l = tid & 63;
    const int nb = (int)gridDim.x, bid = (int)blockIdx.x;
    const int q = nb >> 3;
    const int sw = (bid & 7) * q + (bid >> 3);
    const int bm = (sw / ny) * 128, bn = (sw % ny) * 128;
    const int wr = wv >> 1, wc = wv & 1;
    const int row0 = wv * 32 + (l >> 2);
    const int scol = ((l & 3) ^ ((l >> 3) & 3)) << 4;
    const i8* srcA = A + (size_t)(bm + row0) * lda + scol;
    const i8* srcB = W + (size_t)(bn + row0) * ldw + scol;
#define STG(buf, kt) { \
    const size_t kc = (size_t)(kt) * 64; \
    GLOAD_LDS(srcA + kc,                    &lds[buf][0][wv * 2048]); \
    GLOAD_LDS(srcA + kc + (size_t)16 * lda, &lds[buf][0][wv * 2048 + 1024]); \
    GLOAD_LDS(srcB + kc,                    &lds[buf][1][wv * 2048]); \
    GLOAD_LDS(srcB + kc + (size_t)16 * ldw, &lds[buf][1][wv * 2048 + 1024]); }
    const int swz = ((l >> 4) ^ ((l >> 1) & 3)) << 4;
    const int ab  = (wr * 64 + (l & 15)) * 64 + swz;
    const int bb  = (wc * 64 + (l & 15)) * 64 + swz;
#define RD(pbuf) { \
    _Pragma("unroll") \
    for (int i = 0; i < 4; i++) { \
        a4[i] = *(const i4v*)&lds[pbuf][0][ab + i * 1024]; \
        b4[i] = *(const i4v*)&lds[pbuf][1][bb + i * 1024]; } }
#define MF() { \
    __builtin_amdgcn_s_setprio(1); \
    _Pragma("unroll") \
    for (int mm = 0; mm < 4; mm++) \
        _Pragma("unroll") \
        for (int nn = 0; nn < 4; nn++) \
            acc[mm][nn] = __builtin_amdgcn_mfma_i32_16x16x64_i8( \
                a4[mm], b4[nn], acc[mm][nn], 0, 0, 0); \
    __builtin_amdgcn_s_setprio(0); }

    i4v acc[4][4] = {};
    const int NKT = K >> 6;
    STG(0, 0); STG(1, 1);
    VM4();
    BAR();
    int cur = 0;
    for (int t = 0; t < NKT; ++t) {
        i4v a4[4], b4[4];
        RD(cur);
        const int n2 = cur >= 1 ? cur - 1 : 2;
        if (t + 2 < NKT) STG(n2, t + 2);
        MF();
        if (t + 2 < NKT)      VM4();
        else if (t + 1 < NKT) VM0();
        BAR();
        cur = cur >= 2 ? 0 : cur + 1;
    }
#undef STG
#undef RD
#undef MF
    const int r0 = bm + wr * 64 + ((l >> 4) << 2);
    const int c0 = bn + wc * 64 + (l & 15);
    float sw4[4];
#pragma unroll
    for (int nf = 0; nf < 4; nf++) sw4[nf] = sW[c0 + nf * 16];
#pragma unroll
    for (int mf = 0; mf < 4; mf++)
#pragma unroll
        for (int i = 0; i < 4; i++) {
            const int row = r0 + mf * 16 + i;
            const float sar = sA[row];
#pragma unroll
            for (int nf = 0; nf < 4; nf++) {
                const int col = c0 + nf * 16;
                float r = (float)acc[mf][nf][i] * sar * sw4[nf];
                if (EPI == 3) {
                    size_t o = (size_t)row * ldc + col;
                    ((float*)outv)[o] = fmaf(b2f(e1[o]), r, e0[o]);
                }
            }
        }
}

// ---------------- WKV helpers ----------------
__device__ __forceinline__ void wkv_step(float& a, float& b, float& m,
                                         float w, float kt, float vt)
{
    float mm = fmaxf(m + w, kt);
    float e1 = __expf(m + w - mm);
    float e2 = __expf(kt - mm);
    a = e1 * a + e2 * vt;
    b = e1 * b + e2;
    m = mm;
}
__device__ __forceinline__ void wkv_merge(float& a, float& b, float& m,
                                          float shift, float a2, float b2, float m2)
{
    float ms = m + shift;
    float mm = fmaxf(ms, m2);
    float e1 = __expf(ms - mm);
    float e2 = __expf(m2 - mm);
    a = e1 * a + e2 * a2;
    b = e1 * b + e2 * b2;
    m = mm;
}

// ---------------- WKV pass 1: per-chunk summaries, direction-split ----------------
__global__ __launch_bounds__(256) void wkv_pass1(const u16* __restrict__ kvs,
    const float* __restrict__ decay, float* __restrict__ sums)
{
    int e = blockIdx.x * 256 + threadIdx.x;
    const int PN = NCHK * BC;
    int dir = e / PN, r = e % PN;
    int idx = r % BC, ci = r / BC;
    int b = idx / Cv, c = idx % Cv;
    float w = decay[c] * (1.f / (float)Tv);
    size_t base = ((size_t)b * Tv + (size_t)ci * Lc) * KVS + c;
    const size_t P = (size_t)NCHK * BC;
    size_t so = (size_t)ci * BC + idx;
    float a = 0.f, bb = 0.f, m = -1e38f;
    if (dir == 0) {
        for (int t = 0; t < Lc; t++) {
            size_t off = base + (size_t)t * KVS;
            wkv_step(a, bb, m, w, b2f(kvs[off]), b2f(kvs[off + 768]));
        }
        sums[0 * P + so] = a; sums[1 * P + so] = bb; sums[2 * P + so] = m;
    } else {
        for (int t = Lc - 1; t >= 0; t--) {
            size_t off = base + (size_t)t * KVS;
            wkv_step(a, bb, m, w, b2f(kvs[off]), b2f(kvs[off + 768]));
        }
        sums[3 * P + so] = a; sums[4 * P + so] = bb; sums[5 * P + so] = m;
    }
}

// ---------------- WKV pass 2: scan chunk summaries, direction-split ----------------
__global__ __launch_bounds__(256) void wkv_pass2(const float* __restrict__ decay,
    const float* __restrict__ sums, float* __restrict__ chks)
{
    int e = blockIdx.x * 256 + threadIdx.x;
    int dir = e / BC, idx = e % BC;
    int c = idx % Cv;
    float shift = decay[c] * (1.f / (float)Tv) * (float)Lc;
    const size_t P = (size_t)NCHK * BC;
    float a = 0.f, bb = 0.f, m = -1e38f;
    if (dir == 0) {
        for (int ci = 0; ci < NCHK; ci++) {
            size_t so = (size_t)ci * BC + idx;
            chks[0 * P + so] = a; chks[1 * P + so] = bb; chks[2 * P + so] = m;
            wkv_merge(a, bb, m, shift, sums[0 * P + so], sums[1 * P + so], sums[2 * P + so]);
        }
    } else {
        for (int ci = NCHK - 1; ci >= 0; ci--) {
            size_t so = (size_t)ci * BC + idx;
            chks[3 * P + so] = a; chks[4 * P + so] = bb; chks[5 * P + so] = m;
            wkv_merge(a, bb, m, shift, sums[3 * P + so], sums[4 * P + so], sums[5 * P + so]);
        }
    }
}

// ---------------- WKV pass 3: per-chunk combine, writes y*sr over k slot ----------------
__global__ __launch_bounds__(256) void wkv_pass3(u16* __restrict__ kvs,
    const float* __restrict__ decay, const float* __restrict__ first,
    const float* __restrict__ chks)
{
    int e = blockIdx.x * 256 + threadIdx.x;
    int idx = e % BC, ci = e / BC;
    int b = idx / Cv, c = idx % Cv;
    float w = decay[c] * (1.f / (float)Tv);
    float u = first[c] * (1.f / (float)Tv);
    const size_t P = (size_t)NCHK * BC;
    size_t so = (size_t)ci * BC + idx;
    size_t base = ((size_t)b * Tv + (size_t)ci * Lc) * KVS + c;
    float sa = chks[3 * P + so], sb2 = chks[4 * P + so], sm = chks[5 * P + so];
    float Ba[SI], Bb[SI], Bm[SI];
#pragma unroll
    for (int si = SI - 1; si >= 0; si--) {
        Ba[si] = sa; Bb[si] = sb2; Bm[si] = sm;
        for (int j = 15; j >= 0; j--) {
            size_t off = base + (size_t)(si * 16 + j) * KVS;
            wkv_step(sa, sb2, sm, w, b2f(kvs[off]), b2f(kvs[off + 768]));
        }
    }
    float fa = chks[0 * P + so], fb2 = chks[1 * P + so], fm = chks[2 * P + so];
#pragma unroll
    for (int si = 0; si < SI; si++) {
        float lk[16], lv[16], la[16], lb[16], lm[16];
        float ta = Ba[si], tb = Bb[si], tm = Bm[si];
#pragma unroll
        for (int j = 15; j >= 0; j--) {
            size_t off = base + (size_t)(si * 16 + j) * KVS;
            lk[j] = b2f(kvs[off]); lv[j] = b2f(kvs[off + 768]);
            la[j] = ta; lb[j] = tb; lm[j] = tm;
            wkv_step(ta, tb, tm, w, lk[j], lv[j]);
        }
#pragma unroll
        for (int j = 0; j < 16; j++) {
            float kk = lk[j] + u;
            float M  = fmaxf(fmaxf(fm, lm[j]), kk);
            float ef = __expf(fm - M);
            float eb = __expf(lm[j] - M);
            float ec = __expf(kk - M);
            float num = ef * fa + eb * la[j] + ec * lv[j];
            float den = ef * fb2 + eb * lb[j] + ec;
            size_t off = base + (size_t)(si * 16 + j) * KVS;
            kvs[off] = f2b(b2f(kvs[off + 1536]) * (num / den));  // y' = sr * y
            wkv_step(fa, fb2, fm, w, lk[j], lv[j]);
        }
    }
}

__global__ __launch_bounds__(256) void fill_signal(float* __restrict__ out, int n, float val)
{
    int i = blockIdx.x * 256 + threadIdx.x;
    if (i < n) out[i] = val;
}

extern "C" void kernel_launch(void* const* d_in, const int* in_sizes, int n_in,
                              void* d_out, int out_size, void* d_ws, size_t ws_size,
                              hipStream_t stream)
{
    const float* x     = (const float*)d_in[0];
    const float* ln1_w = (const float*)d_in[1];
    const float* ln1_b = (const float*)d_in[2];
    const float* ln2_w = (const float*)d_in[3];
    const float* ln2_b = (const float*)d_in[4];
    const float* decay = (const float*)d_in[5];
    const float* first = (const float*)d_in[6];
    const float* Wk_a  = (const float*)d_in[7];
    const float* Wv_a  = (const float*)d_in[8];
    const float* Wr_a  = (const float*)d_in[9];
    const float* Wo_a  = (const float*)d_in[10];
    const float* Wk_f  = (const float*)d_in[11];
    const float* Wv_f  = (const float*)d_in[12];
    const float* Wr_f  = (const float*)d_in[13];
    float* out = (float*)d_out;

    const size_t NCe = (size_t)BT * Cv;        // 12,582,912
    const size_t HC  = (size_t)Hv * Cv;
    const size_t SUM = (size_t)6 * NCHK * BC;
    const int    MCH = 4096;                   // FFN chunk rows (4 chunks)
    const int    WR  = 6912;                   // stacked K=768 weight rows

    char* p = (char*)d_ws;
    i8*  h8    = (i8*)p;            p += NCe;                 // h1 / y8 / h2 (serial reuse)
    u16* kvs   = (u16*)p;           p += 3 * NCe * 2;         // k|v|sr bf16 (stride 2304)
    float* x1  = (float*)p;         p += NCe * 4;             // fp32 x after attention
    i8*  wAll  = (i8*)p;            p += (size_t)WR * Cv;     // stacked K=768 weights i8
    i8*  wVf8  = (i8*)p;            p += (size_t)Cv * Hv;     // Wv_f i8
    float* sums = (float*)p;        p += SUM * 4;
    float* chks = (float*)p;        p += SUM * 4;
    float* sAct = (float*)p;        p += (size_t)BT * 4;      // h / h2 row scales
    float* sY   = (float*)p;        p += (size_t)BT * 4;      // y' row scales
    float* sKf  = (float*)p;        p += (size_t)MCH * 4;     // kf chunk row scales
    float* sWall = (float*)p;       p += (size_t)WR * 4;
    float* sWv  = (float*)p;        p += (size_t)Cv * 4;
    size_t need = (size_t)(p - (char*)d_ws);

    if (ws_size < need) {
        fill_signal<<<(int)((NCe + 255) / 256), 256, 0, stream>>>(out, (int)NCe, (float)(ws_size >> 20));
        return;
    }

    // overlays into dead kvs region (after quant_y + Wo-GEMM):
    u16* gate  = kvs;                          // BT x 768 bf16
    u16* kf_c  = kvs + NCe;                    // MCH x 3072 bf16 (chunk)
    i8*  kf_8  = (i8*)(kvs + 2 * NCe);         // MCH x 3072 i8 (chunk)

    dim3 blk(256);
    quant_w6<<<WR, blk, 0, stream>>>(Wk_a, Wv_a, Wr_a, Wo_a, Wk_f, Wr_f, wAll, sWall);
    quant_w1<<<Cv, blk, 0, stream>>>(Wv_f, wVf8, sWv, Hv);

    // 1. h = LN1(x) -> i8 + row scales
    ln_q8<<<BT, blk, 0, stream>>>(x, ln1_w, ln1_b, h8, sAct);
    // 2. fused [k|v|sr] = h @ [Wk;Wv;Wr]^T (i8, 256^2), sigmoid cols >= 1536. grid 576
    gemm256q<0><<<dim3((BT / 256) * (KVS / 256)), blk, 0, stream>>>(
        h8, wAll, kvs, nullptr, Cv, Cv, Cv, KVS, 0, KVS / 256, 1536,
        sAct, sWall, nullptr);
    // 3. bidirectional WKV; y' = sr*y written over k slot
    wkv_pass1<<<(2 * BC * NCHK) / 256, blk, 0, stream>>>(kvs, decay, sums);
    wkv_pass2<<<(2 * BC) / 256, blk, 0, stream>>>(decay, sums, chks);
    wkv_pass3<<<(BC * NCHK) / 256, blk, 0, stream>>>(kvs, decay, first, chks);
    // 4. y' -> i8; x1 = x + y8 @ Wo^T (256^2). grid 192
    quant_y<<<BT, blk, 0, stream>>>(kvs, h8, sY);
    gemm256q<4><<<dim3((BT / 256) * (Cv / 256)), blk, 0, stream>>>(
        h8, wAll + (size_t)2304 * Cv, x1, nullptr, Cv, Cv, Cv, Cv, 0, Cv / 256, 0,
        sY, sWall + 2304, x);
    // 5. h2 = LN2(x1) -> i8 + row scales
    ln_q8<<<BT, blk, 0, stream>>>(x1, ln2_w, ln2_b, h8, sAct);
    // 6. FFN in 4 chunks: fused up+gate (256^2 i8) -> quant kf -> down (128^2 i8)
    for (int j = 0; j < 4; j++) {
        size_t ro = (size_t)j * MCH;
        gemm256q<5><<<dim3((MCH / 256) * ((Hv + Cv) / 256)), blk, 0, stream>>>(
            h8 + ro * Cv, wAll + (size_t)3072 * Cv, kf_c, gate + ro * Cv,
            Cv, Cv, Cv, Hv, Cv, (Hv + Cv) / 256, Hv, sAct + ro, sWall + 3072,
            nullptr);
        quant_bf<<<MCH, blk, 0, stream>>>(kf_c, kf_8, sKf, Hv);
        gemm128q<3><<<dim3((MCH / 128) * (Cv / 128)), blk, 0, stream>>>(
            kf_8, wVf8, out + ro * Cv, Hv, Hv, Hv, Cv, Cv / 128,
            sKf, sWv, x1 + ro * Cv, gate + ro * Cv);
    }
}

// Round 12
// 474.557 us; speedup vs baseline: 1.2343x; 1.2343x over previous
//
#include <hip/hip_runtime.h>
#include <math.h>

typedef unsigned short u16;
typedef signed char i8;
typedef short s8v __attribute__((ext_vector_type(8)));   // 8 bf16
typedef float f4v __attribute__((ext_vector_type(4)));
typedef int   i4v __attribute__((ext_vector_type(4)));   // 16 i8 / 4 i32 acc

constexpr int Bv = 8, Tv = 2048, Cv = 768, Hv = 3072;
constexpr int BT = Bv * Tv;       // 16384 tokens
constexpr int BC = Bv * Cv;       // 6144 channels
constexpr int Lc = 32;            // WKV chunk length
constexpr int NCHK = Tv / Lc;     // 64 chunks
constexpr int SI = Lc / 16;       // 2 sub-chunks
constexpr int KVS = 2304;         // fused k|v|sr row stride

__device__ __forceinline__ float b2f(u16 x) { return __uint_as_float(((unsigned)x) << 16); }
__device__ __forceinline__ u16 f2b(float f) {
    unsigned u = __float_as_uint(f);
    return (u16)((u + 0x7fffu + ((u >> 16) & 1u)) >> 16);   // RNE
}

#define GLOAD_LDS(g, l) __builtin_amdgcn_global_load_lds( \
    (const __attribute__((address_space(1))) void*)(g),    \
    (__attribute__((address_space(3))) void*)(l), 16, 0, 0)
#define BAR()  __builtin_amdgcn_s_barrier()
#define VM4()  asm volatile("s_waitcnt vmcnt(4)" ::: "memory")
#define VM6()  asm volatile("s_waitcnt vmcnt(6)" ::: "memory")
#define VM0()  asm volatile("s_waitcnt vmcnt(0)" ::: "memory")

// ---------------- LayerNorm fp32 -> per-row int8 + scale ----------------
__global__ __launch_bounds__(256) void ln_q8(const float* __restrict__ x,
    const float* __restrict__ w, const float* __restrict__ b,
    i8* __restrict__ outq, float* __restrict__ sA)
{
    __shared__ float sh[8];
    int row = blockIdx.x;
    const float* xr = x + (size_t)row * Cv;
    float vals[3];
    float s = 0.f, s2 = 0.f;
#pragma unroll
    for (int i = 0; i < 3; i++) {
        float t = xr[threadIdx.x + 256 * i];
        vals[i] = t; s += t; s2 += t * t;
    }
#pragma unroll
    for (int off = 32; off > 0; off >>= 1) {
        s  += __shfl_down(s, off);
        s2 += __shfl_down(s2, off);
    }
    int wid = threadIdx.x >> 6;
    if ((threadIdx.x & 63) == 0) { sh[wid] = s; sh[4 + wid] = s2; }
    __syncthreads();
    if (threadIdx.x == 0) {
        sh[0] = sh[0] + sh[1] + sh[2] + sh[3];
        sh[4] = sh[4] + sh[5] + sh[6] + sh[7];
    }
    __syncthreads();
    float mean = sh[0] * (1.f / Cv);
    float var  = sh[4] * (1.f / Cv) - mean * mean;
    float rstd = rsqrtf(var + 1e-5f);
    float nv[3], am = 0.f;
#pragma unroll
    for (int i = 0; i < 3; i++) {
        int j = threadIdx.x + 256 * i;
        nv[i] = (vals[i] - mean) * rstd * w[j] + b[j];
        am = fmaxf(am, fabsf(nv[i]));
    }
#pragma unroll
    for (int off = 32; off > 0; off >>= 1) am = fmaxf(am, __shfl_xor(am, off));
    __syncthreads();
    if ((threadIdx.x & 63) == 0) sh[wid] = am;
    __syncthreads();
    am = fmaxf(fmaxf(sh[0], sh[1]), fmaxf(sh[2], sh[3]));
    am = fmaxf(am, 1e-20f);
    float inv = 127.f / am;
    if (threadIdx.x == 0) sA[row] = am * (1.f / 127.f);
    i8* orow = outq + (size_t)row * Cv;
#pragma unroll
    for (int i = 0; i < 3; i++)
        orow[threadIdx.x + 256 * i] = (i8)(int)rintf(nv[i] * inv);
}

// ---------------- all six K=768 weights -> one stacked i8 buffer ----------------
__global__ __launch_bounds__(256) void quant_w6(const float* __restrict__ wk,
    const float* __restrict__ wv, const float* __restrict__ wr,
    const float* __restrict__ wo, const float* __restrict__ wkf,
    const float* __restrict__ wrf, i8* __restrict__ dst, float* __restrict__ sW)
{
    __shared__ float sh[4];
    int row = blockIdx.x;
    const float* src;
    if      (row < 768)  src = wk  + (size_t)row * Cv;
    else if (row < 1536) src = wv  + (size_t)(row - 768) * Cv;
    else if (row < 2304) src = wr  + (size_t)(row - 1536) * Cv;
    else if (row < 3072) src = wo  + (size_t)(row - 2304) * Cv;
    else if (row < 6144) src = wkf + (size_t)(row - 3072) * Cv;
    else                 src = wrf + (size_t)(row - 6144) * Cv;
    i8* dr = dst + (size_t)row * Cv;
    float am = 0.f;
    for (int j = threadIdx.x; j < Cv; j += 256) am = fmaxf(am, fabsf(src[j]));
#pragma unroll
    for (int off = 32; off > 0; off >>= 1) am = fmaxf(am, __shfl_xor(am, off));
    int wid = threadIdx.x >> 6;
    if ((threadIdx.x & 63) == 0) sh[wid] = am;
    __syncthreads();
    am = fmaxf(fmaxf(sh[0], sh[1]), fmaxf(sh[2], sh[3]));
    am = fmaxf(am, 1e-20f);
    float inv = 127.f / am;
    if (threadIdx.x == 0) sW[row] = am * (1.f / 127.f);
    for (int j = threadIdx.x; j < Cv; j += 256) dr[j] = (i8)(int)rintf(src[j] * inv);
}

// ---------------- single fp32 weight (K=3072) -> i8 ----------------
__global__ __launch_bounds__(256) void quant_w1(const float* __restrict__ src0,
    i8* __restrict__ dst, float* __restrict__ sW, int K)
{
    __shared__ float sh[4];
    int row = blockIdx.x;
    const float* src = src0 + (size_t)row * K;
    i8* dr = dst + (size_t)row * K;
    float am = 0.f;
    for (int j = threadIdx.x; j < K; j += 256) am = fmaxf(am, fabsf(src[j]));
#pragma unroll
    for (int off = 32; off > 0; off >>= 1) am = fmaxf(am, __shfl_xor(am, off));
    int wid = threadIdx.x >> 6;
    if ((threadIdx.x & 63) == 0) sh[wid] = am;
    __syncthreads();
    am = fmaxf(fmaxf(sh[0], sh[1]), fmaxf(sh[2], sh[3]));
    am = fmaxf(am, 1e-20f);
    float inv = 127.f / am;
    if (threadIdx.x == 0) sW[row] = am * (1.f / 127.f);
    for (int j = threadIdx.x; j < K; j += 256) dr[j] = (i8)(int)rintf(src[j] * inv);
}

// ---------------- per-row bf16 -> i8 (kf), vectorized ----------------
__global__ __launch_bounds__(256) void quant_bf(const u16* __restrict__ src,
    i8* __restrict__ dst, float* __restrict__ sA, int K)
{
    __shared__ float sh[4];
    int row = blockIdx.x;
    const u16* sr_ = src + (size_t)row * K;
    i8* dr = dst + (size_t)row * K;
    float am = 0.f;
    for (int j = threadIdx.x * 8; j < K; j += 2048) {
        s8v v = *(const s8v*)(sr_ + j);
#pragma unroll
        for (int b = 0; b < 8; b++) am = fmaxf(am, fabsf(b2f((u16)v[b])));
    }
#pragma unroll
    for (int off = 32; off > 0; off >>= 1) am = fmaxf(am, __shfl_xor(am, off));
    int wid = threadIdx.x >> 6;
    if ((threadIdx.x & 63) == 0) sh[wid] = am;
    __syncthreads();
    am = fmaxf(fmaxf(sh[0], sh[1]), fmaxf(sh[2], sh[3]));
    am = fmaxf(am, 1e-20f);
    float inv = 127.f / am;
    if (threadIdx.x == 0) sA[row] = am * (1.f / 127.f);
    for (int j = threadIdx.x * 8; j < K; j += 2048) {
        s8v v = *(const s8v*)(sr_ + j);
        unsigned lo = 0, hi = 0;
#pragma unroll
        for (int b = 0; b < 4; b++) {
            lo |= ((unsigned)(unsigned char)(i8)(int)rintf(b2f((u16)v[b]) * inv)) << (8 * b);
            hi |= ((unsigned)(unsigned char)(i8)(int)rintf(b2f((u16)v[4 + b]) * inv)) << (8 * b);
        }
        uint2 o2; o2.x = lo; o2.y = hi;
        *(uint2*)(dr + j) = o2;
    }
}

// ---------------- y' (bf16, stride KVS) -> per-row i8 + scale ----------------
__global__ __launch_bounds__(256) void quant_y(const u16* __restrict__ kvs,
    i8* __restrict__ y8, float* __restrict__ sY)
{
    __shared__ float sh[4];
    int row = blockIdx.x;
    const u16* yr = kvs + (size_t)row * KVS;
    float v[3], am = 0.f;
#pragma unroll
    for (int i = 0; i < 3; i++) {
        v[i] = b2f(yr[threadIdx.x + 256 * i]);
        am = fmaxf(am, fabsf(v[i]));
    }
#pragma unroll
    for (int off = 32; off > 0; off >>= 1) am = fmaxf(am, __shfl_xor(am, off));
    int wid = threadIdx.x >> 6;
    if ((threadIdx.x & 63) == 0) sh[wid] = am;
    __syncthreads();
    am = fmaxf(fmaxf(sh[0], sh[1]), fmaxf(sh[2], sh[3]));
    am = fmaxf(am, 1e-20f);
    float inv = 127.f / am;
    if (threadIdx.x == 0) sY[row] = am * (1.f / 127.f);
    i8* orow = y8 + (size_t)row * Cv;
#pragma unroll
    for (int i = 0; i < 3; i++)
        orow[threadIdx.x + 256 * i] = (i8)(int)rintf(v[i] * inv);
}

// ---------------- int8 MFMA GEMM, 256x128 / 8x4-per-wave, 2 blocks/CU --------------
// BM=256, BN=128, BK=64, 256 thr = 4 waves (2x2); per-wave C = 128x64, acc[8][4]
// (128 VGPR; total ~210 < 256 -> 2 waves/SIMD via __launch_bounds__(256,2)).
// LDS: 3 bufs x (A 256x64 + B 128x64) = 72 KiB -> 2 blocks/CU (8 waves/CU).
// Reuse 0.375 ds_read/MFMA: per phase-CU LDS ~1290 cyc ~= MFMA 1305 -> MFMA-bound.
// Per phase: 12 ds_read | stage tile t+2 (6 gload_lds) | 32 MFMA | vmcnt(6) | BAR.
// 3-buffer 1-barrier schedule + swizzle slot^=(row>>1)&3 (formulas unchanged:
// all row-base terms vanish mod 4 after >>1). Grid 1-D nb=(M/256)*(N/128), nb%8==0.
// EPI 0: bf16 out, sigmoid col>=sigoff | 4: f32 e0+r | 5: dual kf/gate
template<int EPI>
__global__ __launch_bounds__(256, 2) void gemm256h(const i8* __restrict__ A,
    const i8* __restrict__ W, void* __restrict__ outv, void* __restrict__ out2,
    int K, int lda, int ldw, int ldc, int ldc2, int ny, int sigoff,
    const float* __restrict__ sA, const float* __restrict__ sW,
    const float* __restrict__ e0)
{
    __shared__ i8 ldsA[3][16384];              // [buf][256*64]
    __shared__ i8 ldsB[3][8192];               // [buf][128*64]
    const int tid = threadIdx.x;
    const int wv = tid >> 6, l = tid & 63;
    const int nb = (int)gridDim.x, bid = (int)blockIdx.x;
    const int q = nb >> 3;
    const int sw = (bid & 7) * q + (bid >> 3);
    const int bm = (sw / ny) * 256, bn = (sw % ny) * 128;
    const int wr = wv >> 1, wc = wv & 1;
    // staging: A wave slab = 64 rows (4 gloads), B wave slab = 32 rows (2 gloads)
    const int rowA = wv * 64 + (l >> 2);
    const int rowB = wv * 32 + (l >> 2);
    const int scol = ((l & 3) ^ ((l >> 3) & 3)) << 4;        // swizzled 16B slot
    const i8* srcA = A + (size_t)(bm + rowA) * lda + scol;
    const i8* srcB = W + (size_t)(bn + rowB) * ldw + scol;
#define STG(buf, kt) { \
    const size_t kc = (size_t)(kt) * 64; \
    GLOAD_LDS(srcA + kc,                    &ldsA[buf][wv * 4096]); \
    GLOAD_LDS(srcA + kc + (size_t)16 * lda, &ldsA[buf][wv * 4096 + 1024]); \
    GLOAD_LDS(srcA + kc + (size_t)32 * lda, &ldsA[buf][wv * 4096 + 2048]); \
    GLOAD_LDS(srcA + kc + (size_t)48 * lda, &ldsA[buf][wv * 4096 + 3072]); \
    GLOAD_LDS(srcB + kc,                    &ldsB[buf][wv * 2048]); \
    GLOAD_LDS(srcB + kc + (size_t)16 * ldw, &ldsB[buf][wv * 2048 + 1024]); }
    // fragment reads: row=(l&15)+16*frag, k-slot (l>>4), swizzled
    const int swz = ((l >> 4) ^ ((l >> 1) & 3)) << 4;
    const int ab  = (wr * 128 + (l & 15)) * 64 + swz;
    const int bb  = (wc * 64 + (l & 15)) * 64 + swz;
#define RD(pbuf) { \
    _Pragma("unroll") \
    for (int i = 0; i < 8; i++) a4[i] = *(const i4v*)&ldsA[pbuf][ab + i * 1024]; \
    _Pragma("unroll") \
    for (int i = 0; i < 4; i++) b4[i] = *(const i4v*)&ldsB[pbuf][bb + i * 1024]; }
#define MF() { \
    __builtin_amdgcn_s_setprio(1); \
    _Pragma("unroll") \
    for (int mm = 0; mm < 8; mm++) \
        _Pragma("unroll") \
        for (int nn = 0; nn < 4; nn++) \
            acc[mm][nn] = __builtin_amdgcn_mfma_i32_16x16x64_i8( \
                a4[mm], b4[nn], acc[mm][nn], 0, 0, 0); \
    __builtin_amdgcn_s_setprio(0); }

    i4v acc[8][4] = {};
    const int NKT = K >> 6;
    STG(0, 0); STG(1, 1);
    VM6();                                     // tile 0's 6 loads landed
    BAR();
    int cur = 0;
    for (int t = 0; t < NKT; ++t) {
        i4v a4[8], b4[4];
        RD(cur);
        const int n2 = cur >= 1 ? cur - 1 : 2;             // (cur+2)%3
        if (t + 2 < NKT) STG(n2, t + 2);
        MF();
        if (t + 2 < NKT)      VM6();           // tile t+1 landed (issued 1 phase ago)
        else if (t + 1 < NKT) VM0();
        BAR();
        cur = cur >= 2 ? 0 : cur + 1;
    }
#undef STG
#undef RD
#undef MF
    // epilogue: C row=(lane>>4)*4+i, col=lane&15 per 16x16 fragment
    const int r0 = bm + wr * 128 + ((l >> 4) << 2);
    const int c0 = bn + wc * 64 + (l & 15);
    float sw4[4];
#pragma unroll
    for (int nf = 0; nf < 4; nf++) sw4[nf] = sW[c0 + nf * 16];
#pragma unroll
    for (int mf = 0; mf < 8; mf++)
#pragma unroll
        for (int i = 0; i < 4; i++) {
            const int row = r0 + mf * 16 + i;
            const float sar = sA[row];
#pragma unroll
            for (int nf = 0; nf < 4; nf++) {
                const int col = c0 + nf * 16;
                float r = (float)acc[mf][nf][i] * sar * sw4[nf];
                if (EPI == 0) {
                    if (col >= sigoff) r = 1.f / (1.f + __expf(-r));
                    ((u16*)outv)[(size_t)row * ldc + col] = f2b(r);
                } else if (EPI == 4) {
                    size_t o = (size_t)row * ldc + col;
                    ((float*)outv)[o] = e0[o] + r;
                } else if (EPI == 5) {
                    if (col < sigoff) {
                        float t2 = fmaxf(r, 0.f);
                        ((u16*)outv)[(size_t)row * ldc + col] = f2b(t2 * t2);
                    } else {
                        float sg = 1.f / (1.f + __expf(-r));
                        ((u16*)out2)[(size_t)row * ldc2 + (col - sigoff)] = f2b(sg);
                    }
                }
            }
        }
}

// ---------------- int8 MFMA GEMM, 128x128 / 3 blocks/CU (round-10 proven; FFN down) --
template<int EPI>
__global__ __launch_bounds__(256, 3) void gemm128q(const i8* __restrict__ A,
    const i8* __restrict__ W, void* __restrict__ outv,
    int K, int lda, int ldw, int ldc, int ny,
    const float* __restrict__ sA, const float* __restrict__ sW,
    const float* __restrict__ e0, const u16* __restrict__ e1)
{
    __shared__ i8 lds[3][2][8192];             // [buf][A/B][128*64]
    const int tid = threadIdx.x;
    const int wv = tid >> 6, l = tid & 63;
    const int nb = (int)gridDim.x, bid = (int)blockIdx.x;
    const int q = nb >> 3;
    const int sw = (bid & 7) * q + (bid >> 3);
    const int bm = (sw / ny) * 128, bn = (sw % ny) * 128;
    const int wr = wv >> 1, wc = wv & 1;
    const int row0 = wv * 32 + (l >> 2);
    const int scol = ((l & 3) ^ ((l >> 3) & 3)) << 4;
    const i8* srcA = A + (size_t)(bm + row0) * lda + scol;
    const i8* srcB = W + (size_t)(bn + row0) * ldw + scol;
#define STG(buf, kt) { \
    const size_t kc = (size_t)(kt) * 64; \
    GLOAD_LDS(srcA + kc,                    &lds[buf][0][wv * 2048]); \
    GLOAD_LDS(srcA + kc + (size_t)16 * lda, &lds[buf][0][wv * 2048 + 1024]); \
    GLOAD_LDS(srcB + kc,                    &lds[buf][1][wv * 2048]); \
    GLOAD_LDS(srcB + kc + (size_t)16 * ldw, &lds[buf][1][wv * 2048 + 1024]); }
    const int swz = ((l >> 4) ^ ((l >> 1) & 3)) << 4;
    const int ab  = (wr * 64 + (l & 15)) * 64 + swz;
    const int bb  = (wc * 64 + (l & 15)) * 64 + swz;
#define RD(pbuf) { \
    _Pragma("unroll") \
    for (int i = 0; i < 4; i++) { \
        a4[i] = *(const i4v*)&lds[pbuf][0][ab + i * 1024]; \
        b4[i] = *(const i4v*)&lds[pbuf][1][bb + i * 1024]; } }
#define MF() { \
    __builtin_amdgcn_s_setprio(1); \
    _Pragma("unroll") \
    for (int mm = 0; mm < 4; mm++) \
        _Pragma("unroll") \
        for (int nn = 0; nn < 4; nn++) \
            acc[mm][nn] = __builtin_amdgcn_mfma_i32_16x16x64_i8( \
                a4[mm], b4[nn], acc[mm][nn], 0, 0, 0); \
    __builtin_amdgcn_s_setprio(0); }

    i4v acc[4][4] = {};
    const int NKT = K >> 6;
    STG(0, 0); STG(1, 1);
    VM4();
    BAR();
    int cur = 0;
    for (int t = 0; t < NKT; ++t) {
        i4v a4[4], b4[4];
        RD(cur);
        const int n2 = cur >= 1 ? cur - 1 : 2;
        if (t + 2 < NKT) STG(n2, t + 2);
        MF();
        if (t + 2 < NKT)      VM4();
        else if (t + 1 < NKT) VM0();
        BAR();
        cur = cur >= 2 ? 0 : cur + 1;
    }
#undef STG
#undef RD
#undef MF
    const int r0 = bm + wr * 64 + ((l >> 4) << 2);
    const int c0 = bn + wc * 64 + (l & 15);
    float sw4[4];
#pragma unroll
    for (int nf = 0; nf < 4; nf++) sw4[nf] = sW[c0 + nf * 16];
#pragma unroll
    for (int mf = 0; mf < 4; mf++)
#pragma unroll
        for (int i = 0; i < 4; i++) {
            const int row = r0 + mf * 16 + i;
            const float sar = sA[row];
#pragma unroll
            for (int nf = 0; nf < 4; nf++) {
                const int col = c0 + nf * 16;
                float r = (float)acc[mf][nf][i] * sar * sw4[nf];
                if (EPI == 3) {
                    size_t o = (size_t)row * ldc + col;
                    ((float*)outv)[o] = fmaf(b2f(e1[o]), r, e0[o]);
                }
            }
        }
}

// ---------------- WKV helpers ----------------
__device__ __forceinline__ void wkv_step(float& a, float& b, float& m,
                                         float w, float kt, float vt)
{
    float mm = fmaxf(m + w, kt);
    float e1 = __expf(m + w - mm);
    float e2 = __expf(kt - mm);
    a = e1 * a + e2 * vt;
    b = e1 * b + e2;
    m = mm;
}
__device__ __forceinline__ void wkv_merge(float& a, float& b, float& m,
                                          float shift, float a2, float b2, float m2)
{
    float ms = m + shift;
    float mm = fmaxf(ms, m2);
    float e1 = __expf(ms - mm);
    float e2 = __expf(m2 - mm);
    a = e1 * a + e2 * a2;
    b = e1 * b + e2 * b2;
    m = mm;
}

// ---------------- WKV pass 1: per-chunk summaries, direction-split ----------------
__global__ __launch_bounds__(256) void wkv_pass1(const u16* __restrict__ kvs,
    const float* __restrict__ decay, float* __restrict__ sums)
{
    int e = blockIdx.x * 256 + threadIdx.x;
    const int PN = NCHK * BC;
    int dir = e / PN, r = e % PN;
    int idx = r % BC, ci = r / BC;
    int b = idx / Cv, c = idx % Cv;
    float w = decay[c] * (1.f / (float)Tv);
    size_t base = ((size_t)b * Tv + (size_t)ci * Lc) * KVS + c;
    const size_t P = (size_t)NCHK * BC;
    size_t so = (size_t)ci * BC + idx;
    float a = 0.f, bb = 0.f, m = -1e38f;
    if (dir == 0) {
        for (int t = 0; t < Lc; t++) {
            size_t off = base + (size_t)t * KVS;
            wkv_step(a, bb, m, w, b2f(kvs[off]), b2f(kvs[off + 768]));
        }
        sums[0 * P + so] = a; sums[1 * P + so] = bb; sums[2 * P + so] = m;
    } else {
        for (int t = Lc - 1; t >= 0; t--) {
            size_t off = base + (size_t)t * KVS;
            wkv_step(a, bb, m, w, b2f(kvs[off]), b2f(kvs[off + 768]));
        }
        sums[3 * P + so] = a; sums[4 * P + so] = bb; sums[5 * P + so] = m;
    }
}

// ---------------- WKV pass 2: scan chunk summaries, direction-split ----------------
__global__ __launch_bounds__(256) void wkv_pass2(const float* __restrict__ decay,
    const float* __restrict__ sums, float* __restrict__ chks)
{
    int e = blockIdx.x * 256 + threadIdx.x;
    int dir = e / BC, idx = e % BC;
    int c = idx % Cv;
    float shift = decay[c] * (1.f / (float)Tv) * (float)Lc;
    const size_t P = (size_t)NCHK * BC;
    float a = 0.f, bb = 0.f, m = -1e38f;
    if (dir == 0) {
        for (int ci = 0; ci < NCHK; ci++) {
            size_t so = (size_t)ci * BC + idx;
            chks[0 * P + so] = a; chks[1 * P + so] = bb; chks[2 * P + so] = m;
            wkv_merge(a, bb, m, shift, sums[0 * P + so], sums[1 * P + so], sums[2 * P + so]);
        }
    } else {
        for (int ci = NCHK - 1; ci >= 0; ci--) {
            size_t so = (size_t)ci * BC + idx;
            chks[3 * P + so] = a; chks[4 * P + so] = bb; chks[5 * P + so] = m;
            wkv_merge(a, bb, m, shift, sums[3 * P + so], sums[4 * P + so], sums[5 * P + so]);
        }
    }
}

// ---------------- WKV pass 3: per-chunk combine, writes y*sr over k slot ----------------
__global__ __launch_bounds__(256) void wkv_pass3(u16* __restrict__ kvs,
    const float* __restrict__ decay, const float* __restrict__ first,
    const float* __restrict__ chks)
{
    int e = blockIdx.x * 256 + threadIdx.x;
    int idx = e % BC, ci = e / BC;
    int b = idx / Cv, c = idx % Cv;
    float w = decay[c] * (1.f / (float)Tv);
    float u = first[c] * (1.f / (float)Tv);
    const size_t P = (size_t)NCHK * BC;
    size_t so = (size_t)ci * BC + idx;
    size_t base = ((size_t)b * Tv + (size_t)ci * Lc) * KVS + c;
    float sa = chks[3 * P + so], sb2 = chks[4 * P + so], sm = chks[5 * P + so];
    float Ba[SI], Bb[SI], Bm[SI];
#pragma unroll
    for (int si = SI - 1; si >= 0; si--) {
        Ba[si] = sa; Bb[si] = sb2; Bm[si] = sm;
        for (int j = 15; j >= 0; j--) {
            size_t off = base + (size_t)(si * 16 + j) * KVS;
            wkv_step(sa, sb2, sm, w, b2f(kvs[off]), b2f(kvs[off + 768]));
        }
    }
    float fa = chks[0 * P + so], fb2 = chks[1 * P + so], fm = chks[2 * P + so];
#pragma unroll
    for (int si = 0; si < SI; si++) {
        float lk[16], lv[16], la[16], lb[16], lm[16];
        float ta = Ba[si], tb = Bb[si], tm = Bm[si];
#pragma unroll
        for (int j = 15; j >= 0; j--) {
            size_t off = base + (size_t)(si * 16 + j) * KVS;
            lk[j] = b2f(kvs[off]); lv[j] = b2f(kvs[off + 768]);
            la[j] = ta; lb[j] = tb; lm[j] = tm;
            wkv_step(ta, tb, tm, w, lk[j], lv[j]);
        }
#pragma unroll
        for (int j = 0; j < 16; j++) {
            float kk = lk[j] + u;
            float M  = fmaxf(fmaxf(fm, lm[j]), kk);
            float ef = __expf(fm - M);
            float eb = __expf(lm[j] - M);
            float ec = __expf(kk - M);
            float num = ef * fa + eb * la[j] + ec * lv[j];
            float den = ef * fb2 + eb * lb[j] + ec;
            size_t off = base + (size_t)(si * 16 + j) * KVS;
            kvs[off] = f2b(b2f(kvs[off + 1536]) * (num / den));  // y' = sr * y
            wkv_step(fa, fb2, fm, w, lk[j], lv[j]);
        }
    }
}

__global__ __launch_bounds__(256) void fill_signal(float* __restrict__ out, int n, float val)
{
    int i = blockIdx.x * 256 + threadIdx.x;
    if (i < n) out[i] = val;
}

extern "C" void kernel_launch(void* const* d_in, const int* in_sizes, int n_in,
                              void* d_out, int out_size, void* d_ws, size_t ws_size,
                              hipStream_t stream)
{
    const float* x     = (const float*)d_in[0];
    const float* ln1_w = (const float*)d_in[1];
    const float* ln1_b = (const float*)d_in[2];
    const float* ln2_w = (const float*)d_in[3];
    const float* ln2_b = (const float*)d_in[4];
    const float* decay = (const float*)d_in[5];
    const float* first = (const float*)d_in[6];
    const float* Wk_a  = (const float*)d_in[7];
    const float* Wv_a  = (const float*)d_in[8];
    const float* Wr_a  = (const float*)d_in[9];
    const float* Wo_a  = (const float*)d_in[10];
    const float* Wk_f  = (const float*)d_in[11];
    const float* Wv_f  = (const float*)d_in[12];
    const float* Wr_f  = (const float*)d_in[13];
    float* out = (float*)d_out;

    const size_t NCe = (size_t)BT * Cv;        // 12,582,912
    const size_t HC  = (size_t)Hv * Cv;
    const size_t SUM = (size_t)6 * NCHK * BC;
    const int    MCH = 4096;                   // FFN chunk rows (4 chunks)
    const int    WR  = 6912;                   // stacked K=768 weight rows

    char* p = (char*)d_ws;
    i8*  h8    = (i8*)p;            p += NCe;                 // h1 / y8 / h2 (serial reuse)
    u16* kvs   = (u16*)p;           p += 3 * NCe * 2;         // k|v|sr bf16 (stride 2304)
    float* x1  = (float*)p;         p += NCe * 4;             // fp32 x after attention
    i8*  wAll  = (i8*)p;            p += (size_t)WR * Cv;     // stacked K=768 weights i8
    i8*  wVf8  = (i8*)p;            p += (size_t)Cv * Hv;     // Wv_f i8
    float* sums = (float*)p;        p += SUM * 4;
    float* chks = (float*)p;        p += SUM * 4;
    float* sAct = (float*)p;        p += (size_t)BT * 4;      // h / h2 row scales
    float* sY   = (float*)p;        p += (size_t)BT * 4;      // y' row scales
    float* sKf  = (float*)p;        p += (size_t)MCH * 4;     // kf chunk row scales
    float* sWall = (float*)p;       p += (size_t)WR * 4;
    float* sWv  = (float*)p;        p += (size_t)Cv * 4;
    size_t need = (size_t)(p - (char*)d_ws);

    if (ws_size < need) {
        fill_signal<<<(int)((NCe + 255) / 256), 256, 0, stream>>>(out, (int)NCe, (float)(ws_size >> 20));
        return;
    }

    // overlays into dead kvs region (after quant_y + Wo-GEMM):
    u16* gate  = kvs;                          // BT x 768 bf16
    u16* kf_c  = kvs + NCe;                    // MCH x 3072 bf16 (chunk)
    i8*  kf_8  = (i8*)(kvs + 2 * NCe);         // MCH x 3072 i8 (chunk)

    dim3 blk(256);
    quant_w6<<<WR, blk, 0, stream>>>(Wk_a, Wv_a, Wr_a, Wo_a, Wk_f, Wr_f, wAll, sWall);
    quant_w1<<<Cv, blk, 0, stream>>>(Wv_f, wVf8, sWv, Hv);

    // 1. h = LN1(x) -> i8 + row scales
    ln_q8<<<BT, blk, 0, stream>>>(x, ln1_w, ln1_b, h8, sAct);
    // 2. fused [k|v|sr] = h @ [Wk;Wv;Wr]^T (256x128 i8), sigmoid cols >= 1536. grid 1152
    gemm256h<0><<<dim3((BT / 256) * (KVS / 128)), blk, 0, stream>>>(
        h8, wAll, kvs, nullptr, Cv, Cv, Cv, KVS, 0, KVS / 128, 1536,
        sAct, sWall, nullptr);
    // 3. bidirectional WKV; y' = sr*y written over k slot
    wkv_pass1<<<(2 * BC * NCHK) / 256, blk, 0, stream>>>(kvs, decay, sums);
    wkv_pass2<<<(2 * BC) / 256, blk, 0, stream>>>(decay, sums, chks);
    wkv_pass3<<<(BC * NCHK) / 256, blk, 0, stream>>>(kvs, decay, first, chks);
    // 4. y' -> i8; x1 = x + y8 @ Wo^T (256x128). grid 384
    quant_y<<<BT, blk, 0, stream>>>(kvs, h8, sY);
    gemm256h<4><<<dim3((BT / 256) * (Cv / 128)), blk, 0, stream>>>(
        h8, wAll + (size_t)2304 * Cv, x1, nullptr, Cv, Cv, Cv, Cv, 0, Cv / 128, 0,
        sY, sWall + 2304, x);
    // 5. h2 = LN2(x1) -> i8 + row scales
    ln_q8<<<BT, blk, 0, stream>>>(x1, ln2_w, ln2_b, h8, sAct);
    // 6. FFN in 4 chunks: fused up+gate (256x128 i8) -> quant kf -> down (128^2 i8)
    for (int j = 0; j < 4; j++) {
        size_t ro = (size_t)j * MCH;
        gemm256h<5><<<dim3((MCH / 256) * ((Hv + Cv) / 128)), blk, 0, stream>>>(
            h8 + ro * Cv, wAll + (size_t)3072 * Cv, kf_c, gate + ro * Cv,
            Cv, Cv, Cv, Hv, Cv, (Hv + Cv) / 128, Hv, sAct + ro, sWall + 3072,
            nullptr);
        quant_bf<<<MCH, blk, 0, stream>>>(kf_c, kf_8, sKf, Hv);
        gemm128q<3><<<dim3((MCH / 128) * (Cv / 128)), blk, 0, stream>>>(
            kf_8, wVf8, out + ro * Cv, Hv, Hv, Hv, Cv, Cv / 128,
            sKf, sWv, x1 + ro * Cv, gate + ro * Cv);
    }
}

// Round 13
// 425.813 us; speedup vs baseline: 1.3756x; 1.1145x over previous
//
#include <hip/hip_runtime.h>
#include <math.h>

typedef unsigned short u16;
typedef signed char i8;
typedef short s8v __attribute__((ext_vector_type(8)));   // 8 bf16
typedef float f4v __attribute__((ext_vector_type(4)));
typedef int   i4v __attribute__((ext_vector_type(4)));   // 16 i8 / 4 i32 acc

constexpr int Bv = 8, Tv = 2048, Cv = 768, Hv = 3072;
constexpr int BT = Bv * Tv;       // 16384 tokens
constexpr int BC = Bv * Cv;       // 6144 channels
constexpr int Lc = 32;            // WKV chunk length
constexpr int NCHK = Tv / Lc;     // 64 chunks
constexpr int SI = Lc / 16;       // 2 sub-chunks
constexpr int KVS = 2304;         // fused k|v|sr row stride
constexpr int NG = Hv / 64;       // 48 kf K-groups

__device__ __forceinline__ float b2f(u16 x) { return __uint_as_float(((unsigned)x) << 16); }
__device__ __forceinline__ u16 f2b(float f) {
    unsigned u = __float_as_uint(f);
    return (u16)((u + 0x7fffu + ((u >> 16) & 1u)) >> 16);   // RNE
}

#define GLOAD_LDS(g, l) __builtin_amdgcn_global_load_lds( \
    (const __attribute__((address_space(1))) void*)(g),    \
    (__attribute__((address_space(3))) void*)(l), 16, 0, 0)
#define BAR()  __builtin_amdgcn_s_barrier()
#define VM4()  asm volatile("s_waitcnt vmcnt(4)" ::: "memory")
#define VM0()  asm volatile("s_waitcnt vmcnt(0)" ::: "memory")

// ---------------- LayerNorm fp32 -> per-row int8 + scale ----------------
__global__ __launch_bounds__(256) void ln_q8(const float* __restrict__ x,
    const float* __restrict__ w, const float* __restrict__ b,
    i8* __restrict__ outq, float* __restrict__ sA)
{
    __shared__ float sh[8];
    int row = blockIdx.x;
    const float* xr = x + (size_t)row * Cv;
    float vals[3];
    float s = 0.f, s2 = 0.f;
#pragma unroll
    for (int i = 0; i < 3; i++) {
        float t = xr[threadIdx.x + 256 * i];
        vals[i] = t; s += t; s2 += t * t;
    }
#pragma unroll
    for (int off = 32; off > 0; off >>= 1) {
        s  += __shfl_down(s, off);
        s2 += __shfl_down(s2, off);
    }
    int wid = threadIdx.x >> 6;
    if ((threadIdx.x & 63) == 0) { sh[wid] = s; sh[4 + wid] = s2; }
    __syncthreads();
    if (threadIdx.x == 0) {
        sh[0] = sh[0] + sh[1] + sh[2] + sh[3];
        sh[4] = sh[4] + sh[5] + sh[6] + sh[7];
    }
    __syncthreads();
    float mean = sh[0] * (1.f / Cv);
    float var  = sh[4] * (1.f / Cv) - mean * mean;
    float rstd = rsqrtf(var + 1e-5f);
    float nv[3], am = 0.f;
#pragma unroll
    for (int i = 0; i < 3; i++) {
        int j = threadIdx.x + 256 * i;
        nv[i] = (vals[i] - mean) * rstd * w[j] + b[j];
        am = fmaxf(am, fabsf(nv[i]));
    }
#pragma unroll
    for (int off = 32; off > 0; off >>= 1) am = fmaxf(am, __shfl_xor(am, off));
    __syncthreads();
    if ((threadIdx.x & 63) == 0) sh[wid] = am;
    __syncthreads();
    am = fmaxf(fmaxf(sh[0], sh[1]), fmaxf(sh[2], sh[3]));
    am = fmaxf(am, 1e-20f);
    float inv = 127.f / am;
    if (threadIdx.x == 0) sA[row] = am * (1.f / 127.f);
    i8* orow = outq + (size_t)row * Cv;
#pragma unroll
    for (int i = 0; i < 3; i++)
        orow[threadIdx.x + 256 * i] = (i8)(int)rintf(nv[i] * inv);
}

// ---------------- all six K=768 weights -> one stacked i8 buffer ----------------
__global__ __launch_bounds__(256) void quant_w6(const float* __restrict__ wk,
    const float* __restrict__ wv, const float* __restrict__ wr,
    const float* __restrict__ wo, const float* __restrict__ wkf,
    const float* __restrict__ wrf, i8* __restrict__ dst, float* __restrict__ sW)
{
    __shared__ float sh[4];
    int row = blockIdx.x;
    const float* src;
    if      (row < 768)  src = wk  + (size_t)row * Cv;
    else if (row < 1536) src = wv  + (size_t)(row - 768) * Cv;
    else if (row < 2304) src = wr  + (size_t)(row - 1536) * Cv;
    else if (row < 3072) src = wo  + (size_t)(row - 2304) * Cv;
    else if (row < 6144) src = wkf + (size_t)(row - 3072) * Cv;
    else                 src = wrf + (size_t)(row - 6144) * Cv;
    i8* dr = dst + (size_t)row * Cv;
    float am = 0.f;
    for (int j = threadIdx.x; j < Cv; j += 256) am = fmaxf(am, fabsf(src[j]));
#pragma unroll
    for (int off = 32; off > 0; off >>= 1) am = fmaxf(am, __shfl_xor(am, off));
    int wid = threadIdx.x >> 6;
    if ((threadIdx.x & 63) == 0) sh[wid] = am;
    __syncthreads();
    am = fmaxf(fmaxf(sh[0], sh[1]), fmaxf(sh[2], sh[3]));
    am = fmaxf(am, 1e-20f);
    float inv = 127.f / am;
    if (threadIdx.x == 0) sW[row] = am * (1.f / 127.f);
    for (int j = threadIdx.x; j < Cv; j += 256) dr[j] = (i8)(int)rintf(src[j] * inv);
}

// ---------------- single fp32 weight (K=3072) -> i8 ----------------
__global__ __launch_bounds__(256) void quant_w1(const float* __restrict__ src0,
    i8* __restrict__ dst, float* __restrict__ sW, int K)
{
    __shared__ float sh[4];
    int row = blockIdx.x;
    const float* src = src0 + (size_t)row * K;
    i8* dr = dst + (size_t)row * K;
    float am = 0.f;
    for (int j = threadIdx.x; j < K; j += 256) am = fmaxf(am, fabsf(src[j]));
#pragma unroll
    for (int off = 32; off > 0; off >>= 1) am = fmaxf(am, __shfl_xor(am, off));
    int wid = threadIdx.x >> 6;
    if ((threadIdx.x & 63) == 0) sh[wid] = am;
    __syncthreads();
    am = fmaxf(fmaxf(sh[0], sh[1]), fmaxf(sh[2], sh[3]));
    am = fmaxf(am, 1e-20f);
    float inv = 127.f / am;
    if (threadIdx.x == 0) sW[row] = am * (1.f / 127.f);
    for (int j = threadIdx.x; j < K; j += 256) dr[j] = (i8)(int)rintf(src[j] * inv);
}

// ---------------- y' (bf16, stride KVS) -> per-row i8 + scale ----------------
__global__ __launch_bounds__(256) void quant_y(const u16* __restrict__ kvs,
    i8* __restrict__ y8, float* __restrict__ sY)
{
    __shared__ float sh[4];
    int row = blockIdx.x;
    const u16* yr = kvs + (size_t)row * KVS;
    float v[3], am = 0.f;
#pragma unroll
    for (int i = 0; i < 3; i++) {
        v[i] = b2f(yr[threadIdx.x + 256 * i]);
        am = fmaxf(am, fabsf(v[i]));
    }
#pragma unroll
    for (int off = 32; off > 0; off >>= 1) am = fmaxf(am, __shfl_xor(am, off));
    int wid = threadIdx.x >> 6;
    if ((threadIdx.x & 63) == 0) sh[wid] = am;
    __syncthreads();
    am = fmaxf(fmaxf(sh[0], sh[1]), fmaxf(sh[2], sh[3]));
    am = fmaxf(am, 1e-20f);
    float inv = 127.f / am;
    if (threadIdx.x == 0) sY[row] = am * (1.f / 127.f);
    i8* orow = y8 + (size_t)row * Cv;
#pragma unroll
    for (int i = 0; i < 3; i++)
        orow[threadIdx.x + 256 * i] = (i8)(int)rintf(v[i] * inv);
}

// ---------------- int8 MFMA GEMM, 128x128 / 3 blocks/CU (round-10 proven) ----------
// Per phase: 8 ds_read | stage tile t+2 (4 gload_lds) | 16 MFMA | vmcnt(4) | BAR.
// EPI 0: bf16 out, sigmoid col>=sigoff (kvs)
// EPI 4: f32 out = e0 + r (Wo)
// EPI 6: FFN up+gate: cols < sigoff -> relu(r)^2 group-quant i8 (64-col groups,
//        in-wave shfl_xor max) to outv(ldc) + sG[row][g]; cols >= sigoff ->
//        sigmoid bf16 to out2(ldc2).
template<int EPI>
__global__ __launch_bounds__(256, 3) void gemm128q(const i8* __restrict__ A,
    const i8* __restrict__ W, void* __restrict__ outv, void* __restrict__ out2,
    int K, int lda, int ldw, int ldc, int ldc2, int ny, int sigoff,
    const float* __restrict__ sA, const float* __restrict__ sW,
    const float* __restrict__ e0, float* __restrict__ sG)
{
    __shared__ i8 lds[3][2][8192];             // [buf][A/B][128*64]
    const int tid = threadIdx.x;
    const int wv = tid >> 6, l = tid & 63;
    const int nb = (int)gridDim.x, bid = (int)blockIdx.x;
    const int q = nb >> 3;
    const int sw = (bid & 7) * q + (bid >> 3);
    const int bm = (sw / ny) * 128, bn = (sw % ny) * 128;
    const int wr = wv >> 1, wc = wv & 1;
    const int row0 = wv * 32 + (l >> 2);
    const int scol = ((l & 3) ^ ((l >> 3) & 3)) << 4;
    const i8* srcA = A + (size_t)(bm + row0) * lda + scol;
    const i8* srcB = W + (size_t)(bn + row0) * ldw + scol;
#define STG(buf, kt) { \
    const size_t kc = (size_t)(kt) * 64; \
    GLOAD_LDS(srcA + kc,                    &lds[buf][0][wv * 2048]); \
    GLOAD_LDS(srcA + kc + (size_t)16 * lda, &lds[buf][0][wv * 2048 + 1024]); \
    GLOAD_LDS(srcB + kc,                    &lds[buf][1][wv * 2048]); \
    GLOAD_LDS(srcB + kc + (size_t)16 * ldw, &lds[buf][1][wv * 2048 + 1024]); }
    const int swz = ((l >> 4) ^ ((l >> 1) & 3)) << 4;
    const int ab  = (wr * 64 + (l & 15)) * 64 + swz;
    const int bb  = (wc * 64 + (l & 15)) * 64 + swz;
#define RD(pbuf) { \
    _Pragma("unroll") \
    for (int i = 0; i < 4; i++) { \
        a4[i] = *(const i4v*)&lds[pbuf][0][ab + i * 1024]; \
        b4[i] = *(const i4v*)&lds[pbuf][1][bb + i * 1024]; } }
#define MF() { \
    __builtin_amdgcn_s_setprio(1); \
    _Pragma("unroll") \
    for (int mm = 0; mm < 4; mm++) \
        _Pragma("unroll") \
        for (int nn = 0; nn < 4; nn++) \
            acc[mm][nn] = __builtin_amdgcn_mfma_i32_16x16x64_i8( \
                a4[mm], b4[nn], acc[mm][nn], 0, 0, 0); \
    __builtin_amdgcn_s_setprio(0); }

    i4v acc[4][4] = {};
    const int NKT = K >> 6;
    STG(0, 0); STG(1, 1);
    VM4();
    BAR();
    int cur = 0;
    for (int t = 0; t < NKT; ++t) {
        i4v a4[4], b4[4];
        RD(cur);
        const int n2 = cur >= 1 ? cur - 1 : 2;
        if (t + 2 < NKT) STG(n2, t + 2);
        MF();
        if (t + 2 < NKT)      VM4();
        else if (t + 1 < NKT) VM0();
        BAR();
        cur = cur >= 2 ? 0 : cur + 1;
    }
#undef STG
#undef RD
#undef MF
    // epilogue: C row=(lane>>4)*4+i, col=lane&15 per 16x16 fragment
    const int r0 = bm + wr * 64 + ((l >> 4) << 2);
    const int c0 = bn + wc * 64 + (l & 15);
    float sw4[4];
#pragma unroll
    for (int nf = 0; nf < 4; nf++) sw4[nf] = sW[c0 + nf * 16];
    if (EPI == 6 && bn < sigoff) {
        // kf block: relu^2, per-(row, 64-col-group) quantize to i8
        const int g = (bn + wc * 64) >> 6;
        i8* kf8 = (i8*)outv;
#pragma unroll
        for (int mf = 0; mf < 4; mf++)
#pragma unroll
            for (int i = 0; i < 4; i++) {
                const int row = r0 + mf * 16 + i;
                const float sar = sA[row];
                float v[4], amx = 0.f;
#pragma unroll
                for (int nf = 0; nf < 4; nf++) {
                    float r = (float)acc[mf][nf][i] * sar * sw4[nf];
                    r = fmaxf(r, 0.f);
                    v[nf] = r * r;
                    amx = fmaxf(amx, v[nf]);
                }
#pragma unroll
                for (int off = 8; off >= 1; off >>= 1)
                    amx = fmaxf(amx, __shfl_xor(amx, off));   // max over 16 col-lanes
                amx = fmaxf(amx, 1e-20f);
                float inv = 127.f / amx;
#pragma unroll
                for (int nf = 0; nf < 4; nf++)
                    kf8[(size_t)row * ldc + (c0 + nf * 16)] = (i8)(int)rintf(v[nf] * inv);
                if ((l & 15) == 0) sG[(size_t)row * NG + g] = amx * (1.f / 127.f);
            }
        return;
    }
#pragma unroll
    for (int mf = 0; mf < 4; mf++)
#pragma unroll
        for (int i = 0; i < 4; i++) {
            const int row = r0 + mf * 16 + i;
            const float sar = sA[row];
#pragma unroll
            for (int nf = 0; nf < 4; nf++) {
                const int col = c0 + nf * 16;
                float r = (float)acc[mf][nf][i] * sar * sw4[nf];
                if (EPI == 0) {
                    if (col >= sigoff) r = 1.f / (1.f + __expf(-r));
                    ((u16*)outv)[(size_t)row * ldc + col] = f2b(r);
                } else if (EPI == 4) {
                    size_t o = (size_t)row * ldc + col;
                    ((float*)outv)[o] = e0[o] + r;
                } else if (EPI == 6) {
                    // gate block (bn >= sigoff)
                    float sg = 1.f / (1.f + __expf(-r));
                    ((u16*)out2)[(size_t)row * ldc2 + (col - sigoff)] = f2b(sg);
                }
            }
        }
}

// ---------------- FFN down: i8 GEMM with per-phase K-group rescale ----------------
// A = kf_8 (group-quantized, group = 64 K-cols = one BK phase), W = Wv_f i8.
// Per phase: one MFMA per frag with C=0; facc += float(m) * sG[row][t].
// Epilogue: out = x1 + gate * (facc * sWv[col]).
__global__ __launch_bounds__(256, 3) void gemm128d(const i8* __restrict__ A,
    const i8* __restrict__ W, float* __restrict__ out,
    int K, int lda, int ldw, int ldc, int ny,
    const float* __restrict__ sG, const float* __restrict__ sWv,
    const float* __restrict__ x1, const u16* __restrict__ gate)
{
    __shared__ i8 lds[3][2][8192];
    const int tid = threadIdx.x;
    const int wv = tid >> 6, l = tid & 63;
    const int nb = (int)gridDim.x, bid = (int)blockIdx.x;
    const int q = nb >> 3;
    const int sw = (bid & 7) * q + (bid >> 3);
    const int bm = (sw / ny) * 128, bn = (sw % ny) * 128;
    const int wr = wv >> 1, wc = wv & 1;
    const int row0 = wv * 32 + (l >> 2);
    const int scol = ((l & 3) ^ ((l >> 3) & 3)) << 4;
    const i8* srcA = A + (size_t)(bm + row0) * lda + scol;
    const i8* srcB = W + (size_t)(bn + row0) * ldw + scol;
#define STG(buf, kt) { \
    const size_t kc = (size_t)(kt) * 64; \
    GLOAD_LDS(srcA + kc,                    &lds[buf][0][wv * 2048]); \
    GLOAD_LDS(srcA + kc + (size_t)16 * lda, &lds[buf][0][wv * 2048 + 1024]); \
    GLOAD_LDS(srcB + kc,                    &lds[buf][1][wv * 2048]); \
    GLOAD_LDS(srcB + kc + (size_t)16 * ldw, &lds[buf][1][wv * 2048 + 1024]); }
    const int swz = ((l >> 4) ^ ((l >> 1) & 3)) << 4;
    const int ab  = (wr * 64 + (l & 15)) * 64 + swz;
    const int bb  = (wc * 64 + (l & 15)) * 64 + swz;
#define RD(pbuf) { \
    _Pragma("unroll") \
    for (int i = 0; i < 4; i++) { \
        a4[i] = *(const i4v*)&lds[pbuf][0][ab + i * 1024]; \
        b4[i] = *(const i4v*)&lds[pbuf][1][bb + i * 1024]; } }

    f4v facc[4][4] = {};
    const int NKT = K >> 6;                    // 48 phases = 48 K-groups
    const int r0 = bm + wr * 64 + ((l >> 4) << 2);
    STG(0, 0); STG(1, 1);
    VM4();
    BAR();
    int cur = 0;
    for (int t = 0; t < NKT; ++t) {
        i4v a4[4], b4[4];
        RD(cur);
        const int n2 = cur >= 1 ? cur - 1 : 2;
        if (t + 2 < NKT) STG(n2, t + 2);
        float sg[4][4];
#pragma unroll
        for (int mm = 0; mm < 4; mm++)
#pragma unroll
            for (int i = 0; i < 4; i++)
                sg[mm][i] = sG[(size_t)(r0 + mm * 16 + i) * NG + t];
        __builtin_amdgcn_s_setprio(1);
#pragma unroll
        for (int mm = 0; mm < 4; mm++)
#pragma unroll
            for (int nn = 0; nn < 4; nn++) {
                i4v z = {0, 0, 0, 0};
                i4v m = __builtin_amdgcn_mfma_i32_16x16x64_i8(a4[mm], b4[nn], z, 0, 0, 0);
#pragma unroll
                for (int i = 0; i < 4; i++)
                    facc[mm][nn][i] += (float)m[i] * sg[mm][i];
            }
        __builtin_amdgcn_s_setprio(0);
        if (t + 2 < NKT)      VM4();
        else if (t + 1 < NKT) VM0();
        BAR();
        cur = cur >= 2 ? 0 : cur + 1;
    }
#undef STG
#undef RD
    const int c0 = bn + wc * 64 + (l & 15);
    float sw4[4];
#pragma unroll
    for (int nf = 0; nf < 4; nf++) sw4[nf] = sWv[c0 + nf * 16];
#pragma unroll
    for (int mf = 0; mf < 4; mf++)
#pragma unroll
        for (int i = 0; i < 4; i++) {
            const int row = r0 + mf * 16 + i;
#pragma unroll
            for (int nf = 0; nf < 4; nf++) {
                const int col = c0 + nf * 16;
                size_t o = (size_t)row * ldc + col;
                out[o] = fmaf(b2f(gate[(size_t)row * Cv + col]),
                              facc[mf][nf][i] * sw4[nf], x1[o]);
            }
        }
}

// ---------------- WKV helpers ----------------
__device__ __forceinline__ void wkv_step(float& a, float& b, float& m,
                                         float w, float kt, float vt)
{
    float mm = fmaxf(m + w, kt);
    float e1 = __expf(m + w - mm);
    float e2 = __expf(kt - mm);
    a = e1 * a + e2 * vt;
    b = e1 * b + e2;
    m = mm;
}
__device__ __forceinline__ void wkv_merge(float& a, float& b, float& m,
                                          float shift, float a2, float b2, float m2)
{
    float ms = m + shift;
    float mm = fmaxf(ms, m2);
    float e1 = __expf(ms - mm);
    float e2 = __expf(m2 - mm);
    a = e1 * a + e2 * a2;
    b = e1 * b + e2 * b2;
    m = mm;
}

// ---------------- WKV pass 1: per-chunk summaries, direction-split ----------------
__global__ __launch_bounds__(256) void wkv_pass1(const u16* __restrict__ kvs,
    const float* __restrict__ decay, float* __restrict__ sums)
{
    int e = blockIdx.x * 256 + threadIdx.x;
    const int PN = NCHK * BC;
    int dir = e / PN, r = e % PN;
    int idx = r % BC, ci = r / BC;
    int b = idx / Cv, c = idx % Cv;
    float w = decay[c] * (1.f / (float)Tv);
    size_t base = ((size_t)b * Tv + (size_t)ci * Lc) * KVS + c;
    const size_t P = (size_t)NCHK * BC;
    size_t so = (size_t)ci * BC + idx;
    float a = 0.f, bb = 0.f, m = -1e38f;
    if (dir == 0) {
        for (int t = 0; t < Lc; t++) {
            size_t off = base + (size_t)t * KVS;
            wkv_step(a, bb, m, w, b2f(kvs[off]), b2f(kvs[off + 768]));
        }
        sums[0 * P + so] = a; sums[1 * P + so] = bb; sums[2 * P + so] = m;
    } else {
        for (int t = Lc - 1; t >= 0; t--) {
            size_t off = base + (size_t)t * KVS;
            wkv_step(a, bb, m, w, b2f(kvs[off]), b2f(kvs[off + 768]));
        }
        sums[3 * P + so] = a; sums[4 * P + so] = bb; sums[5 * P + so] = m;
    }
}

// ---------------- WKV pass 2: scan chunk summaries, direction-split ----------------
__global__ __launch_bounds__(256) void wkv_pass2(const float* __restrict__ decay,
    const float* __restrict__ sums, float* __restrict__ chks)
{
    int e = blockIdx.x * 256 + threadIdx.x;
    int dir = e / BC, idx = e % BC;
    int c = idx % Cv;
    float shift = decay[c] * (1.f / (float)Tv) * (float)Lc;
    const size_t P = (size_t)NCHK * BC;
    float a = 0.f, bb = 0.f, m = -1e38f;
    if (dir == 0) {
        for (int ci = 0; ci < NCHK; ci++) {
            size_t so = (size_t)ci * BC + idx;
            chks[0 * P + so] = a; chks[1 * P + so] = bb; chks[2 * P + so] = m;
            wkv_merge(a, bb, m, shift, sums[0 * P + so], sums[1 * P + so], sums[2 * P + so]);
        }
    } else {
        for (int ci = NCHK - 1; ci >= 0; ci--) {
            size_t so = (size_t)ci * BC + idx;
            chks[3 * P + so] = a; chks[4 * P + so] = bb; chks[5 * P + so] = m;
            wkv_merge(a, bb, m, shift, sums[3 * P + so], sums[4 * P + so], sums[5 * P + so]);
        }
    }
}

// ---------------- WKV pass 3: per-chunk combine, writes y*sr over k slot ----------------
__global__ __launch_bounds__(256) void wkv_pass3(u16* __restrict__ kvs,
    const float* __restrict__ decay, const float* __restrict__ first,
    const float* __restrict__ chks)
{
    int e = blockIdx.x * 256 + threadIdx.x;
    int idx = e % BC, ci = e / BC;
    int b = idx / Cv, c = idx % Cv;
    float w = decay[c] * (1.f / (float)Tv);
    float u = first[c] * (1.f / (float)Tv);
    const size_t P = (size_t)NCHK * BC;
    size_t so = (size_t)ci * BC + idx;
    size_t base = ((size_t)b * Tv + (size_t)ci * Lc) * KVS + c;
    float sa = chks[3 * P + so], sb2 = chks[4 * P + so], sm = chks[5 * P + so];
    float Ba[SI], Bb[SI], Bm[SI];
#pragma unroll
    for (int si = SI - 1; si >= 0; si--) {
        Ba[si] = sa; Bb[si] = sb2; Bm[si] = sm;
        for (int j = 15; j >= 0; j--) {
            size_t off = base + (size_t)(si * 16 + j) * KVS;
            wkv_step(sa, sb2, sm, w, b2f(kvs[off]), b2f(kvs[off + 768]));
        }
    }
    float fa = chks[0 * P + so], fb2 = chks[1 * P + so], fm = chks[2 * P + so];
#pragma unroll
    for (int si = 0; si < SI; si++) {
        float lk[16], lv[16], la[16], lb[16], lm[16];
        float ta = Ba[si], tb = Bb[si], tm = Bm[si];
#pragma unroll
        for (int j = 15; j >= 0; j--) {
            size_t off = base + (size_t)(si * 16 + j) * KVS;
            lk[j] = b2f(kvs[off]); lv[j] = b2f(kvs[off + 768]);
            la[j] = ta; lb[j] = tb; lm[j] = tm;
            wkv_step(ta, tb, tm, w, lk[j], lv[j]);
        }
#pragma unroll
        for (int j = 0; j < 16; j++) {
            float kk = lk[j] + u;
            float M  = fmaxf(fmaxf(fm, lm[j]), kk);
            float ef = __expf(fm - M);
            float eb = __expf(lm[j] - M);
            float ec = __expf(kk - M);
            float num = ef * fa + eb * la[j] + ec * lv[j];
            float den = ef * fb2 + eb * lb[j] + ec;
            size_t off = base + (size_t)(si * 16 + j) * KVS;
            kvs[off] = f2b(b2f(kvs[off + 1536]) * (num / den));  // y' = sr * y
            wkv_step(fa, fb2, fm, w, lk[j], lv[j]);
        }
    }
}

__global__ __launch_bounds__(256) void fill_signal(float* __restrict__ out, int n, float val)
{
    int i = blockIdx.x * 256 + threadIdx.x;
    if (i < n) out[i] = val;
}

extern "C" void kernel_launch(void* const* d_in, const int* in_sizes, int n_in,
                              void* d_out, int out_size, void* d_ws, size_t ws_size,
                              hipStream_t stream)
{
    const float* x     = (const float*)d_in[0];
    const float* ln1_w = (const float*)d_in[1];
    const float* ln1_b = (const float*)d_in[2];
    const float* ln2_w = (const float*)d_in[3];
    const float* ln2_b = (const float*)d_in[4];
    const float* decay = (const float*)d_in[5];
    const float* first = (const float*)d_in[6];
    const float* Wk_a  = (const float*)d_in[7];
    const float* Wv_a  = (const float*)d_in[8];
    const float* Wr_a  = (const float*)d_in[9];
    const float* Wo_a  = (const float*)d_in[10];
    const float* Wk_f  = (const float*)d_in[11];
    const float* Wv_f  = (const float*)d_in[12];
    const float* Wr_f  = (const float*)d_in[13];
    float* out = (float*)d_out;

    const size_t NCe = (size_t)BT * Cv;        // 12,582,912
    const size_t HC  = (size_t)Hv * Cv;
    const size_t SUM = (size_t)6 * NCHK * BC;
    const int    WR  = 6912;                   // stacked K=768 weight rows

    char* p = (char*)d_ws;
    i8*  h8    = (i8*)p;            p += NCe;                 // h1 / y8 / h2 (serial reuse)
    u16* kvs   = (u16*)p;           p += 3 * NCe * 2;         // k|v|sr bf16 (stride 2304)
    float* x1  = (float*)p;         p += NCe * 4;             // fp32 x after attention
    i8*  wAll  = (i8*)p;            p += (size_t)WR * Cv;     // stacked K=768 weights i8
    i8*  wVf8  = (i8*)p;            p += (size_t)Cv * Hv;     // Wv_f i8
    float* sums = (float*)p;        p += SUM * 4;
    float* chks = (float*)p;        p += SUM * 4;
    float* sAct = (float*)p;        p += (size_t)BT * 4;      // h / h2 row scales
    float* sY   = (float*)p;        p += (size_t)BT * 4;      // y' row scales
    float* sG   = (float*)p;        p += (size_t)BT * NG * 4; // kf group scales (3.1 MB)
    float* sWall = (float*)p;       p += (size_t)WR * 4;
    float* sWv  = (float*)p;        p += (size_t)Cv * 4;
    size_t need = (size_t)(p - (char*)d_ws);

    if (ws_size < need) {
        fill_signal<<<(int)((NCe + 255) / 256), 256, 0, stream>>>(out, (int)NCe, (float)(ws_size >> 20));
        return;
    }

    // overlays into dead kvs region (after quant_y):
    u16* gate = kvs;                           // BT x 768 bf16   (25.2 MB)
    i8*  kf_8 = (i8*)(kvs + NCe);              // BT x 3072 i8    (50.3 MB) - fills rest

    dim3 blk(256);
    quant_w6<<<WR, blk, 0, stream>>>(Wk_a, Wv_a, Wr_a, Wo_a, Wk_f, Wr_f, wAll, sWall);
    quant_w1<<<Cv, blk, 0, stream>>>(Wv_f, wVf8, sWv, Hv);

    // 1. h = LN1(x) -> i8 + row scales
    ln_q8<<<BT, blk, 0, stream>>>(x, ln1_w, ln1_b, h8, sAct);
    // 2. fused [k|v|sr] = h @ [Wk;Wv;Wr]^T, sigmoid cols >= 1536. grid 2304 = 3.0 rounds
    gemm128q<0><<<dim3((BT / 128) * (KVS / 128)), blk, 0, stream>>>(
        h8, wAll, kvs, nullptr, Cv, Cv, Cv, KVS, 0, KVS / 128, 1536,
        sAct, sWall, nullptr, nullptr);
    // 3. bidirectional WKV; y' = sr*y written over k slot
    wkv_pass1<<<(2 * BC * NCHK) / 256, blk, 0, stream>>>(kvs, decay, sums);
    wkv_pass2<<<(2 * BC) / 256, blk, 0, stream>>>(decay, sums, chks);
    wkv_pass3<<<(BC * NCHK) / 256, blk, 0, stream>>>(kvs, decay, first, chks);
    // 4. y' -> i8; x1 = x + y8 @ Wo^T. grid 768 = 1.0 round
    quant_y<<<BT, blk, 0, stream>>>(kvs, h8, sY);
    gemm128q<4><<<dim3((BT / 128) * (Cv / 128)), blk, 0, stream>>>(
        h8, wAll + (size_t)2304 * Cv, x1, nullptr, Cv, Cv, Cv, Cv, 0, Cv / 128, 0,
        sY, sWall + 2304, x, nullptr);
    // 5. h2 = LN2(x1) -> i8 + row scales
    ln_q8<<<BT, blk, 0, stream>>>(x1, ln2_w, ln2_b, h8, sAct);
    // 6. FFN up+gate, UNCHUNKED: [kf_i8+sG | gate] = h2 @ [Wk_f;Wr_f]^T.
    //    grid 3840 = 5.0 exact rounds. kf group-quantized (64-col groups).
    gemm128q<6><<<dim3((BT / 128) * ((Hv + Cv) / 128)), blk, 0, stream>>>(
        h8, wAll + (size_t)3072 * Cv, kf_8, gate, Cv, Cv, Cv, Hv, Cv,
        (Hv + Cv) / 128, Hv, sAct, sWall + 3072, nullptr, sG);
    // 7. FFN down, UNCHUNKED with per-phase group rescale. grid 768 = 1.0 round
    gemm128d<<<dim3((BT / 128) * (Cv / 128)), blk, 0, stream>>>(
        kf_8, wVf8, out, Hv, Hv, Hv, Cv, Cv / 128, sG, sWv, x1, gate);
}

// Round 14
// 363.516 us; speedup vs baseline: 1.6113x; 1.1714x over previous
//
#include <hip/hip_runtime.h>
#include <math.h>

typedef unsigned short u16;
typedef signed char i8;
typedef short s8v __attribute__((ext_vector_type(8)));   // 8 bf16
typedef float f4v __attribute__((ext_vector_type(4)));
typedef int   i4v __attribute__((ext_vector_type(4)));   // 16 i8 / 4 i32 acc

constexpr int Bv = 8, Tv = 2048, Cv = 768, Hv = 3072;
constexpr int BT = Bv * Tv;       // 16384 tokens
constexpr int BC = Bv * Cv;       // 6144 channels
constexpr int Lc = 32;            // WKV chunk length
constexpr int NCHK = Tv / Lc;     // 64 chunks
constexpr int SI = Lc / 16;       // 2 sub-chunks
constexpr int KVS = 2304;         // fused k|v|sr row stride
constexpr int NG = Hv / 64;       // 48 kf K-groups

__device__ __forceinline__ float b2f(u16 x) { return __uint_as_float(((unsigned)x) << 16); }
__device__ __forceinline__ u16 f2b(float f) {
    unsigned u = __float_as_uint(f);
    return (u16)((u + 0x7fffu + ((u >> 16) & 1u)) >> 16);   // RNE
}

#define GLOAD_LDS(g, l) __builtin_amdgcn_global_load_lds( \
    (const __attribute__((address_space(1))) void*)(g),    \
    (__attribute__((address_space(3))) void*)(l), 16, 0, 0)
#define BAR()  __builtin_amdgcn_s_barrier()
#define VM4()  asm volatile("s_waitcnt vmcnt(4)" ::: "memory")
#define VM0()  asm volatile("s_waitcnt vmcnt(0)" ::: "memory")

// ---------------- LayerNorm fp32 -> per-row int8 + scale ----------------
__global__ __launch_bounds__(256) void ln_q8(const float* __restrict__ x,
    const float* __restrict__ w, const float* __restrict__ b,
    i8* __restrict__ outq, float* __restrict__ sA)
{
    __shared__ float sh[8];
    int row = blockIdx.x;
    const float* xr = x + (size_t)row * Cv;
    float vals[3];
    float s = 0.f, s2 = 0.f;
#pragma unroll
    for (int i = 0; i < 3; i++) {
        float t = xr[threadIdx.x + 256 * i];
        vals[i] = t; s += t; s2 += t * t;
    }
#pragma unroll
    for (int off = 32; off > 0; off >>= 1) {
        s  += __shfl_down(s, off);
        s2 += __shfl_down(s2, off);
    }
    int wid = threadIdx.x >> 6;
    if ((threadIdx.x & 63) == 0) { sh[wid] = s; sh[4 + wid] = s2; }
    __syncthreads();
    if (threadIdx.x == 0) {
        sh[0] = sh[0] + sh[1] + sh[2] + sh[3];
        sh[4] = sh[4] + sh[5] + sh[6] + sh[7];
    }
    __syncthreads();
    float mean = sh[0] * (1.f / Cv);
    float var  = sh[4] * (1.f / Cv) - mean * mean;
    float rstd = rsqrtf(var + 1e-5f);
    float nv[3], am = 0.f;
#pragma unroll
    for (int i = 0; i < 3; i++) {
        int j = threadIdx.x + 256 * i;
        nv[i] = (vals[i] - mean) * rstd * w[j] + b[j];
        am = fmaxf(am, fabsf(nv[i]));
    }
#pragma unroll
    for (int off = 32; off > 0; off >>= 1) am = fmaxf(am, __shfl_xor(am, off));
    __syncthreads();
    if ((threadIdx.x & 63) == 0) sh[wid] = am;
    __syncthreads();
    am = fmaxf(fmaxf(sh[0], sh[1]), fmaxf(sh[2], sh[3]));
    am = fmaxf(am, 1e-20f);
    float inv = 127.f / am;
    if (threadIdx.x == 0) sA[row] = am * (1.f / 127.f);
    i8* orow = outq + (size_t)row * Cv;
#pragma unroll
    for (int i = 0; i < 3; i++)
        orow[threadIdx.x + 256 * i] = (i8)(int)rintf(nv[i] * inv);
}

// ---------------- all six K=768 weights -> one stacked i8 buffer ----------------
__global__ __launch_bounds__(256) void quant_w6(const float* __restrict__ wk,
    const float* __restrict__ wv, const float* __restrict__ wr,
    const float* __restrict__ wo, const float* __restrict__ wkf,
    const float* __restrict__ wrf, i8* __restrict__ dst, float* __restrict__ sW)
{
    __shared__ float sh[4];
    int row = blockIdx.x;
    const float* src;
    if      (row < 768)  src = wk  + (size_t)row * Cv;
    else if (row < 1536) src = wv  + (size_t)(row - 768) * Cv;
    else if (row < 2304) src = wr  + (size_t)(row - 1536) * Cv;
    else if (row < 3072) src = wo  + (size_t)(row - 2304) * Cv;
    else if (row < 6144) src = wkf + (size_t)(row - 3072) * Cv;
    else                 src = wrf + (size_t)(row - 6144) * Cv;
    i8* dr = dst + (size_t)row * Cv;
    float am = 0.f;
    for (int j = threadIdx.x; j < Cv; j += 256) am = fmaxf(am, fabsf(src[j]));
#pragma unroll
    for (int off = 32; off > 0; off >>= 1) am = fmaxf(am, __shfl_xor(am, off));
    int wid = threadIdx.x >> 6;
    if ((threadIdx.x & 63) == 0) sh[wid] = am;
    __syncthreads();
    am = fmaxf(fmaxf(sh[0], sh[1]), fmaxf(sh[2], sh[3]));
    am = fmaxf(am, 1e-20f);
    float inv = 127.f / am;
    if (threadIdx.x == 0) sW[row] = am * (1.f / 127.f);
    for (int j = threadIdx.x; j < Cv; j += 256) dr[j] = (i8)(int)rintf(src[j] * inv);
}

// ---------------- single fp32 weight (K=3072) -> i8 ----------------
__global__ __launch_bounds__(256) void quant_w1(const float* __restrict__ src0,
    i8* __restrict__ dst, float* __restrict__ sW, int K)
{
    __shared__ float sh[4];
    int row = blockIdx.x;
    const float* src = src0 + (size_t)row * K;
    i8* dr = dst + (size_t)row * K;
    float am = 0.f;
    for (int j = threadIdx.x; j < K; j += 256) am = fmaxf(am, fabsf(src[j]));
#pragma unroll
    for (int off = 32; off > 0; off >>= 1) am = fmaxf(am, __shfl_xor(am, off));
    int wid = threadIdx.x >> 6;
    if ((threadIdx.x & 63) == 0) sh[wid] = am;
    __syncthreads();
    am = fmaxf(fmaxf(sh[0], sh[1]), fmaxf(sh[2], sh[3]));
    am = fmaxf(am, 1e-20f);
    float inv = 127.f / am;
    if (threadIdx.x == 0) sW[row] = am * (1.f / 127.f);
    for (int j = threadIdx.x; j < K; j += 256) dr[j] = (i8)(int)rintf(src[j] * inv);
}

// ---------------- y' (bf16, stride KVS) -> per-row i8 + scale ----------------
__global__ __launch_bounds__(256) void quant_y(const u16* __restrict__ kvs,
    i8* __restrict__ y8, float* __restrict__ sY)
{
    __shared__ float sh[4];
    int row = blockIdx.x;
    const u16* yr = kvs + (size_t)row * KVS;
    float v[3], am = 0.f;
#pragma unroll
    for (int i = 0; i < 3; i++) {
        v[i] = b2f(yr[threadIdx.x + 256 * i]);
        am = fmaxf(am, fabsf(v[i]));
    }
#pragma unroll
    for (int off = 32; off > 0; off >>= 1) am = fmaxf(am, __shfl_xor(am, off));
    int wid = threadIdx.x >> 6;
    if ((threadIdx.x & 63) == 0) sh[wid] = am;
    __syncthreads();
    am = fmaxf(fmaxf(sh[0], sh[1]), fmaxf(sh[2], sh[3]));
    am = fmaxf(am, 1e-20f);
    float inv = 127.f / am;
    if (threadIdx.x == 0) sY[row] = am * (1.f / 127.f);
    i8* orow = y8 + (size_t)row * Cv;
#pragma unroll
    for (int i = 0; i < 3; i++)
        orow[threadIdx.x + 256 * i] = (i8)(int)rintf(v[i] * inv);
}

// ---------------- requant kf: group scales -> single per-row scale (in place) -------
// 192 thr = 4 rows x 48 lanes. Per pass p (0..3): thread handles 16 i8 at
// offset p*768 + t*16 (contiguous 768B per pass), group g = 12p + (t>>2).
__global__ __launch_bounds__(192) void requant_kf(i8* __restrict__ kf,
    const float* __restrict__ sG, float* __restrict__ sKf)
{
    int tid = threadIdx.x;
    int row = blockIdx.x * 4 + tid / 48;
    int t = tid % 48;
    const float* sgr = sG + (size_t)row * NG;
    float am = 0.f;
#pragma unroll
    for (int g = 0; g < NG; g++) am = fmaxf(am, sgr[g]);
    if (t == 0) sKf[row] = am;
    float iam = 1.f / am;
    i8* kr = kf + (size_t)row * Hv;
#pragma unroll
    for (int p = 0; p < 4; p++) {
        int off = p * 768 + t * 16;
        float f = sgr[12 * p + (t >> 2)] * iam;
        i4v v = *(const i4v*)(kr + off);
        i4v o;
#pragma unroll
        for (int wq = 0; wq < 4; wq++) {
            unsigned r = 0;
#pragma unroll
            for (int b = 0; b < 4; b++) {
                int q = (int)(i8)((v[wq] >> (8 * b)) & 0xff);
                r |= ((unsigned)(unsigned char)(i8)(int)rintf((float)q * f)) << (8 * b);
            }
            o[wq] = (int)r;
        }
        *(i4v*)(kr + off) = o;
    }
}

// ---------------- int8 MFMA GEMM, 128x128 / 3 blocks/CU (round-10 proven) ----------
// Per phase: 8 ds_read | stage tile t+2 (4 gload_lds) | 16 MFMA | vmcnt(4) | BAR.
// EPI 0: bf16 out, sigmoid col>=sigoff (kvs)
// EPI 3: f32 out = e0 + b2f(e1)*r (FFN down: x1 + gate*r)
// EPI 4: f32 out = e0 + r (Wo)
// EPI 6: FFN up+gate: cols < sigoff -> relu(r)^2 group-quant i8 + sG; else sigmoid bf16
template<int EPI>
__global__ __launch_bounds__(256, 3) void gemm128q(const i8* __restrict__ A,
    const i8* __restrict__ W, void* __restrict__ outv, void* __restrict__ out2,
    int K, int lda, int ldw, int ldc, int ldc2, int ny, int sigoff,
    const float* __restrict__ sA, const float* __restrict__ sW,
    const float* __restrict__ e0, const u16* __restrict__ e1, float* __restrict__ sG)
{
    __shared__ i8 lds[3][2][8192];             // [buf][A/B][128*64]
    const int tid = threadIdx.x;
    const int wv = tid >> 6, l = tid & 63;
    const int nb = (int)gridDim.x, bid = (int)blockIdx.x;
    const int q = nb >> 3;
    const int sw = (bid & 7) * q + (bid >> 3);
    const int bm = (sw / ny) * 128, bn = (sw % ny) * 128;
    const int wr = wv >> 1, wc = wv & 1;
    const int row0 = wv * 32 + (l >> 2);
    const int scol = ((l & 3) ^ ((l >> 3) & 3)) << 4;
    const i8* srcA = A + (size_t)(bm + row0) * lda + scol;
    const i8* srcB = W + (size_t)(bn + row0) * ldw + scol;
#define STG(buf, kt) { \
    const size_t kc = (size_t)(kt) * 64; \
    GLOAD_LDS(srcA + kc,                    &lds[buf][0][wv * 2048]); \
    GLOAD_LDS(srcA + kc + (size_t)16 * lda, &lds[buf][0][wv * 2048 + 1024]); \
    GLOAD_LDS(srcB + kc,                    &lds[buf][1][wv * 2048]); \
    GLOAD_LDS(srcB + kc + (size_t)16 * ldw, &lds[buf][1][wv * 2048 + 1024]); }
    const int swz = ((l >> 4) ^ ((l >> 1) & 3)) << 4;
    const int ab  = (wr * 64 + (l & 15)) * 64 + swz;
    const int bb  = (wc * 64 + (l & 15)) * 64 + swz;
#define RD(pbuf) { \
    _Pragma("unroll") \
    for (int i = 0; i < 4; i++) { \
        a4[i] = *(const i4v*)&lds[pbuf][0][ab + i * 1024]; \
        b4[i] = *(const i4v*)&lds[pbuf][1][bb + i * 1024]; } }
#define MF() { \
    __builtin_amdgcn_s_setprio(1); \
    _Pragma("unroll") \
    for (int mm = 0; mm < 4; mm++) \
        _Pragma("unroll") \
        for (int nn = 0; nn < 4; nn++) \
            acc[mm][nn] = __builtin_amdgcn_mfma_i32_16x16x64_i8( \
                a4[mm], b4[nn], acc[mm][nn], 0, 0, 0); \
    __builtin_amdgcn_s_setprio(0); }

    i4v acc[4][4] = {};
    const int NKT = K >> 6;
    STG(0, 0); STG(1, 1);
    VM4();
    BAR();
    int cur = 0;
    for (int t = 0; t < NKT; ++t) {
        i4v a4[4], b4[4];
        RD(cur);
        const int n2 = cur >= 1 ? cur - 1 : 2;
        if (t + 2 < NKT) STG(n2, t + 2);
        MF();
        if (t + 2 < NKT)      VM4();
        else if (t + 1 < NKT) VM0();
        BAR();
        cur = cur >= 2 ? 0 : cur + 1;
    }
#undef STG
#undef RD
#undef MF
    // epilogue: C row=(lane>>4)*4+i, col=lane&15 per 16x16 fragment
    const int r0 = bm + wr * 64 + ((l >> 4) << 2);
    const int c0 = bn + wc * 64 + (l & 15);
    float sw4[4];
#pragma unroll
    for (int nf = 0; nf < 4; nf++) sw4[nf] = sW[c0 + nf * 16];
    if (EPI == 6 && bn < sigoff) {
        // kf block: relu^2, per-(row, 64-col-group) quantize to i8
        const int g = (bn + wc * 64) >> 6;
        i8* kf8 = (i8*)outv;
#pragma unroll
        for (int mf = 0; mf < 4; mf++)
#pragma unroll
            for (int i = 0; i < 4; i++) {
                const int row = r0 + mf * 16 + i;
                const float sar = sA[row];
                float v[4], amx = 0.f;
#pragma unroll
                for (int nf = 0; nf < 4; nf++) {
                    float r = (float)acc[mf][nf][i] * sar * sw4[nf];
                    r = fmaxf(r, 0.f);
                    v[nf] = r * r;
                    amx = fmaxf(amx, v[nf]);
                }
#pragma unroll
                for (int off = 8; off >= 1; off >>= 1)
                    amx = fmaxf(amx, __shfl_xor(amx, off));   // max over 16 col-lanes
                amx = fmaxf(amx, 1e-20f);
                float inv = 127.f / amx;
#pragma unroll
                for (int nf = 0; nf < 4; nf++)
                    kf8[(size_t)row * ldc + (c0 + nf * 16)] = (i8)(int)rintf(v[nf] * inv);
                if ((l & 15) == 0) sG[(size_t)row * NG + g] = amx * (1.f / 127.f);
            }
        return;
    }
#pragma unroll
    for (int mf = 0; mf < 4; mf++)
#pragma unroll
        for (int i = 0; i < 4; i++) {
            const int row = r0 + mf * 16 + i;
            const float sar = sA[row];
#pragma unroll
            for (int nf = 0; nf < 4; nf++) {
                const int col = c0 + nf * 16;
                float r = (float)acc[mf][nf][i] * sar * sw4[nf];
                if (EPI == 0) {
                    if (col >= sigoff) r = 1.f / (1.f + __expf(-r));
                    ((u16*)outv)[(size_t)row * ldc + col] = f2b(r);
                } else if (EPI == 3) {
                    size_t o = (size_t)row * ldc + col;
                    ((float*)outv)[o] = fmaf(b2f(e1[(size_t)row * Cv + col]), r, e0[o]);
                } else if (EPI == 4) {
                    size_t o = (size_t)row * ldc + col;
                    ((float*)outv)[o] = e0[o] + r;
                } else if (EPI == 6) {
                    // gate block (bn >= sigoff)
                    float sg = 1.f / (1.f + __expf(-r));
                    ((u16*)out2)[(size_t)row * ldc2 + (col - sigoff)] = f2b(sg);
                }
            }
        }
}

// ---------------- WKV helpers ----------------
__device__ __forceinline__ void wkv_step(float& a, float& b, float& m,
                                         float w, float kt, float vt)
{
    float mm = fmaxf(m + w, kt);
    float e1 = __expf(m + w - mm);
    float e2 = __expf(kt - mm);
    a = e1 * a + e2 * vt;
    b = e1 * b + e2;
    m = mm;
}
__device__ __forceinline__ void wkv_merge(float& a, float& b, float& m,
                                          float shift, float a2, float b2, float m2)
{
    float ms = m + shift;
    float mm = fmaxf(ms, m2);
    float e1 = __expf(ms - mm);
    float e2 = __expf(m2 - mm);
    a = e1 * a + e2 * a2;
    b = e1 * b + e2 * b2;
    m = mm;
}

// ---------------- WKV pass 1: per-chunk summaries, direction-split ----------------
__global__ __launch_bounds__(256) void wkv_pass1(const u16* __restrict__ kvs,
    const float* __restrict__ decay, float* __restrict__ sums)
{
    int e = blockIdx.x * 256 + threadIdx.x;
    const int PN = NCHK * BC;
    int dir = e / PN, r = e % PN;
    int idx = r % BC, ci = r / BC;
    int b = idx / Cv, c = idx % Cv;
    float w = decay[c] * (1.f / (float)Tv);
    size_t base = ((size_t)b * Tv + (size_t)ci * Lc) * KVS + c;
    const size_t P = (size_t)NCHK * BC;
    size_t so = (size_t)ci * BC + idx;
    float a = 0.f, bb = 0.f, m = -1e38f;
    if (dir == 0) {
        for (int t = 0; t < Lc; t++) {
            size_t off = base + (size_t)t * KVS;
            wkv_step(a, bb, m, w, b2f(kvs[off]), b2f(kvs[off + 768]));
        }
        sums[0 * P + so] = a; sums[1 * P + so] = bb; sums[2 * P + so] = m;
    } else {
        for (int t = Lc - 1; t >= 0; t--) {
            size_t off = base + (size_t)t * KVS;
            wkv_step(a, bb, m, w, b2f(kvs[off]), b2f(kvs[off + 768]));
        }
        sums[3 * P + so] = a; sums[4 * P + so] = bb; sums[5 * P + so] = m;
    }
}

// ---------------- WKV pass 2: scan chunk summaries, direction-split ----------------
__global__ __launch_bounds__(256) void wkv_pass2(const float* __restrict__ decay,
    const float* __restrict__ sums, float* __restrict__ chks)
{
    int e = blockIdx.x * 256 + threadIdx.x;
    int dir = e / BC, idx = e % BC;
    int c = idx % Cv;
    float shift = decay[c] * (1.f / (float)Tv) * (float)Lc;
    const size_t P = (size_t)NCHK * BC;
    float a = 0.f, bb = 0.f, m = -1e38f;
    if (dir == 0) {
        for (int ci = 0; ci < NCHK; ci++) {
            size_t so = (size_t)ci * BC + idx;
            chks[0 * P + so] = a; chks[1 * P + so] = bb; chks[2 * P + so] = m;
            wkv_merge(a, bb, m, shift, sums[0 * P + so], sums[1 * P + so], sums[2 * P + so]);
        }
    } else {
        for (int ci = NCHK - 1; ci >= 0; ci--) {
            size_t so = (size_t)ci * BC + idx;
            chks[3 * P + so] = a; chks[4 * P + so] = bb; chks[5 * P + so] = m;
            wkv_merge(a, bb, m, shift, sums[3 * P + so], sums[4 * P + so], sums[5 * P + so]);
        }
    }
}

// ---------------- WKV pass 3: per-chunk combine, writes y*sr over k slot ----------------
__global__ __launch_bounds__(256) void wkv_pass3(u16* __restrict__ kvs,
    const float* __restrict__ decay, const float* __restrict__ first,
    const float* __restrict__ chks)
{
    int e = blockIdx.x * 256 + threadIdx.x;
    int idx = e % BC, ci = e / BC;
    int b = idx / Cv, c = idx % Cv;
    float w = decay[c] * (1.f / (float)Tv);
    float u = first[c] * (1.f / (float)Tv);
    const size_t P = (size_t)NCHK * BC;
    size_t so = (size_t)ci * BC + idx;
    size_t base = ((size_t)b * Tv + (size_t)ci * Lc) * KVS + c;
    float sa = chks[3 * P + so], sb2 = chks[4 * P + so], sm = chks[5 * P + so];
    float Ba[SI], Bb[SI], Bm[SI];
#pragma unroll
    for (int si = SI - 1; si >= 0; si--) {
        Ba[si] = sa; Bb[si] = sb2; Bm[si] = sm;
        for (int j = 15; j >= 0; j--) {
            size_t off = base + (size_t)(si * 16 + j) * KVS;
            wkv_step(sa, sb2, sm, w, b2f(kvs[off]), b2f(kvs[off + 768]));
        }
    }
    float fa = chks[0 * P + so], fb2 = chks[1 * P + so], fm = chks[2 * P + so];
#pragma unroll
    for (int si = 0; si < SI; si++) {
        float lk[16], lv[16], la[16], lb[16], lm[16];
        float ta = Ba[si], tb = Bb[si], tm = Bm[si];
#pragma unroll
        for (int j = 15; j >= 0; j--) {
            size_t off = base + (size_t)(si * 16 + j) * KVS;
            lk[j] = b2f(kvs[off]); lv[j] = b2f(kvs[off + 768]);
            la[j] = ta; lb[j] = tb; lm[j] = tm;
            wkv_step(ta, tb, tm, w, lk[j], lv[j]);
        }
#pragma unroll
        for (int j = 0; j < 16; j++) {
            float kk = lk[j] + u;
            float M  = fmaxf(fmaxf(fm, lm[j]), kk);
            float ef = __expf(fm - M);
            float eb = __expf(lm[j] - M);
            float ec = __expf(kk - M);
            float num = ef * fa + eb * la[j] + ec * lv[j];
            float den = ef * fb2 + eb * lb[j] + ec;
            size_t off = base + (size_t)(si * 16 + j) * KVS;
            kvs[off] = f2b(b2f(kvs[off + 1536]) * (num / den));  // y' = sr * y
            wkv_step(fa, fb2, fm, w, lk[j], lv[j]);
        }
    }
}

__global__ __launch_bounds__(256) void fill_signal(float* __restrict__ out, int n, float val)
{
    int i = blockIdx.x * 256 + threadIdx.x;
    if (i < n) out[i] = val;
}

extern "C" void kernel_launch(void* const* d_in, const int* in_sizes, int n_in,
                              void* d_out, int out_size, void* d_ws, size_t ws_size,
                              hipStream_t stream)
{
    const float* x     = (const float*)d_in[0];
    const float* ln1_w = (const float*)d_in[1];
    const float* ln1_b = (const float*)d_in[2];
    const float* ln2_w = (const float*)d_in[3];
    const float* ln2_b = (const float*)d_in[4];
    const float* decay = (const float*)d_in[5];
    const float* first = (const float*)d_in[6];
    const float* Wk_a  = (const float*)d_in[7];
    const float* Wv_a  = (const float*)d_in[8];
    const float* Wr_a  = (const float*)d_in[9];
    const float* Wo_a  = (const float*)d_in[10];
    const float* Wk_f  = (const float*)d_in[11];
    const float* Wv_f  = (const float*)d_in[12];
    const float* Wr_f  = (const float*)d_in[13];
    float* out = (float*)d_out;

    const size_t NCe = (size_t)BT * Cv;        // 12,582,912
    const size_t HC  = (size_t)Hv * Cv;
    const size_t SUM = (size_t)6 * NCHK * BC;
    const int    WR  = 6912;                   // stacked K=768 weight rows

    char* p = (char*)d_ws;
    i8*  h8    = (i8*)p;            p += NCe;                 // h1 / y8 / h2 (serial reuse)
    u16* kvs   = (u16*)p;           p += 3 * NCe * 2;         // k|v|sr bf16 (stride 2304)
    float* x1  = (float*)p;         p += NCe * 4;             // fp32 x after attention
    i8*  wAll  = (i8*)p;            p += (size_t)WR * Cv;     // stacked K=768 weights i8
    i8*  wVf8  = (i8*)p;            p += (size_t)Cv * Hv;     // Wv_f i8
    float* sums = (float*)p;        p += SUM * 4;
    float* chks = (float*)p;        p += SUM * 4;
    float* sAct = (float*)p;        p += (size_t)BT * 4;      // h / h2 row scales
    float* sY   = (float*)p;        p += (size_t)BT * 4;      // y' row scales
    float* sG   = (float*)p;        p += (size_t)BT * NG * 4; // kf group scales (3.1 MB)
    float* sKf  = (float*)p;        p += (size_t)BT * 4;      // kf per-row scales
    float* sWall = (float*)p;       p += (size_t)WR * 4;
    float* sWv  = (float*)p;        p += (size_t)Cv * 4;
    size_t need = (size_t)(p - (char*)d_ws);

    if (ws_size < need) {
        fill_signal<<<(int)((NCe + 255) / 256), 256, 0, stream>>>(out, (int)NCe, (float)(ws_size >> 20));
        return;
    }

    // overlays into dead kvs region (after quant_y):
    u16* gate = kvs;                           // BT x 768 bf16   (25.2 MB)
    i8*  kf_8 = (i8*)(kvs + NCe);              // BT x 3072 i8    (50.3 MB)

    dim3 blk(256);
    quant_w6<<<WR, blk, 0, stream>>>(Wk_a, Wv_a, Wr_a, Wo_a, Wk_f, Wr_f, wAll, sWall);
    quant_w1<<<Cv, blk, 0, stream>>>(Wv_f, wVf8, sWv, Hv);

    // 1. h = LN1(x) -> i8 + row scales
    ln_q8<<<BT, blk, 0, stream>>>(x, ln1_w, ln1_b, h8, sAct);
    // 2. fused [k|v|sr] = h @ [Wk;Wv;Wr]^T, sigmoid cols >= 1536. grid 2304 = 3.0 rounds
    gemm128q<0><<<dim3((BT / 128) * (KVS / 128)), blk, 0, stream>>>(
        h8, wAll, kvs, nullptr, Cv, Cv, Cv, KVS, 0, KVS / 128, 1536,
        sAct, sWall, nullptr, nullptr, nullptr);
    // 3. bidirectional WKV; y' = sr*y written over k slot
    wkv_pass1<<<(2 * BC * NCHK) / 256, blk, 0, stream>>>(kvs, decay, sums);
    wkv_pass2<<<(2 * BC) / 256, blk, 0, stream>>>(decay, sums, chks);
    wkv_pass3<<<(BC * NCHK) / 256, blk, 0, stream>>>(kvs, decay, first, chks);
    // 4. y' -> i8; x1 = x + y8 @ Wo^T. grid 768 = 1.0 round
    quant_y<<<BT, blk, 0, stream>>>(kvs, h8, sY);
    gemm128q<4><<<dim3((BT / 128) * (Cv / 128)), blk, 0, stream>>>(
        h8, wAll + (size_t)2304 * Cv, x1, nullptr, Cv, Cv, Cv, Cv, 0, Cv / 128, 0,
        sY, sWall + 2304, x, nullptr, nullptr);
    // 5. h2 = LN2(x1) -> i8 + row scales
    ln_q8<<<BT, blk, 0, stream>>>(x1, ln2_w, ln2_b, h8, sAct);
    // 6. FFN up+gate, unchunked: [kf_i8+sG | gate] = h2 @ [Wk_f;Wr_f]^T. grid 3840
    gemm128q<6><<<dim3((BT / 128) * ((Hv + Cv) / 128)), blk, 0, stream>>>(
        h8, wAll + (size_t)3072 * Cv, kf_8, gate, Cv, Cv, Cv, Hv, Cv,
        (Hv + Cv) / 128, Hv, sAct, sWall + 3072, nullptr, nullptr, sG);
    // 6b. requant kf: group scales -> per-row scale (in place), ~103 MB traffic
    requant_kf<<<BT / 4, dim3(192), 0, stream>>>(kf_8, sG, sKf);
    // 7. FFN down, pure-int K-loop (r10 structure). grid 768 = 1.0 round
    gemm128q<3><<<dim3((BT / 128) * (Cv / 128)), blk, 0, stream>>>(
        kf_8, wVf8, out, nullptr, Hv, Hv, Hv, Cv, 0, Cv / 128, 0,
        sKf, sWv, x1, gate, nullptr);
}

// Round 15
// 354.903 us; speedup vs baseline: 1.6504x; 1.0243x over previous
//
#include <hip/hip_runtime.h>
#include <math.h>

typedef unsigned short u16;
typedef signed char i8;
typedef short s8v __attribute__((ext_vector_type(8)));   // 8 bf16
typedef float f4v __attribute__((ext_vector_type(4)));
typedef int   i4v __attribute__((ext_vector_type(4)));   // 16 i8 / 4 i32 acc

constexpr int Bv = 8, Tv = 2048, Cv = 768, Hv = 3072;
constexpr int BT = Bv * Tv;       // 16384 tokens
constexpr int BC = Bv * Cv;       // 6144 channels
constexpr int Lc = 32;            // WKV chunk length
constexpr int NCHK = Tv / Lc;     // 64 chunks
constexpr int SI = Lc / 16;       // 2 sub-chunks
constexpr int KVS = 2304;         // fused k|v|sr row stride
constexpr int NG = Hv / 64;       // 48 kf K-groups

__device__ __forceinline__ float b2f(u16 x) { return __uint_as_float(((unsigned)x) << 16); }
__device__ __forceinline__ u16 f2b(float f) {
    unsigned u = __float_as_uint(f);
    return (u16)((u + 0x7fffu + ((u >> 16) & 1u)) >> 16);   // RNE
}

#define GLOAD_LDS(g, l) __builtin_amdgcn_global_load_lds( \
    (const __attribute__((address_space(1))) void*)(g),    \
    (__attribute__((address_space(3))) void*)(l), 16, 0, 0)
#define BAR()  __builtin_amdgcn_s_barrier()
#define VM4()  asm volatile("s_waitcnt vmcnt(4)" ::: "memory")
#define VM0()  asm volatile("s_waitcnt vmcnt(0)" ::: "memory")

// ---------------- LayerNorm (fp32 or bf16 input) -> per-row int8 + scale ------------
template<int BF>
__global__ __launch_bounds__(256) void ln_q8(const void* __restrict__ xin,
    const float* __restrict__ w, const float* __restrict__ b,
    i8* __restrict__ outq, float* __restrict__ sA)
{
    __shared__ float sh[8];
    int row = blockIdx.x;
    float vals[3];
    float s = 0.f, s2 = 0.f;
#pragma unroll
    for (int i = 0; i < 3; i++) {
        int j = threadIdx.x + 256 * i;
        float t = BF ? b2f(((const u16*)xin)[(size_t)row * Cv + j])
                     : ((const float*)xin)[(size_t)row * Cv + j];
        vals[i] = t; s += t; s2 += t * t;
    }
#pragma unroll
    for (int off = 32; off > 0; off >>= 1) {
        s  += __shfl_down(s, off);
        s2 += __shfl_down(s2, off);
    }
    int wid = threadIdx.x >> 6;
    if ((threadIdx.x & 63) == 0) { sh[wid] = s; sh[4 + wid] = s2; }
    __syncthreads();
    if (threadIdx.x == 0) {
        sh[0] = sh[0] + sh[1] + sh[2] + sh[3];
        sh[4] = sh[4] + sh[5] + sh[6] + sh[7];
    }
    __syncthreads();
    float mean = sh[0] * (1.f / Cv);
    float var  = sh[4] * (1.f / Cv) - mean * mean;
    float rstd = rsqrtf(var + 1e-5f);
    float nv[3], am = 0.f;
#pragma unroll
    for (int i = 0; i < 3; i++) {
        int j = threadIdx.x + 256 * i;
        nv[i] = (vals[i] - mean) * rstd * w[j] + b[j];
        am = fmaxf(am, fabsf(nv[i]));
    }
#pragma unroll
    for (int off = 32; off > 0; off >>= 1) am = fmaxf(am, __shfl_xor(am, off));
    __syncthreads();
    if ((threadIdx.x & 63) == 0) sh[wid] = am;
    __syncthreads();
    am = fmaxf(fmaxf(sh[0], sh[1]), fmaxf(sh[2], sh[3]));
    am = fmaxf(am, 1e-20f);
    float inv = 127.f / am;
    if (threadIdx.x == 0) sA[row] = am * (1.f / 127.f);
    i8* orow = outq + (size_t)row * Cv;
#pragma unroll
    for (int i = 0; i < 3; i++)
        orow[threadIdx.x + 256 * i] = (i8)(int)rintf(nv[i] * inv);
}

// ---------------- ALL weights -> i8 (one dispatch) ----------------
// rows [0,6912): K=768 stacked [Wk_a|Wv_a|Wr_a|Wo_a|Wk_f|Wr_f] -> wAll/sWall
// rows [6912,7680): K=3072 Wv_f -> wVf8/sWv
__global__ __launch_bounds__(256) void quant_wAll(const float* __restrict__ wk,
    const float* __restrict__ wv, const float* __restrict__ wr,
    const float* __restrict__ wo, const float* __restrict__ wkf,
    const float* __restrict__ wrf, const float* __restrict__ wvf,
    i8* __restrict__ dstA, float* __restrict__ sWA,
    i8* __restrict__ dstV, float* __restrict__ sWV)
{
    __shared__ float sh[4];
    int row = blockIdx.x;
    const float* src;
    i8* dr;
    float* sp;
    int K;
    if (row < 6912) {
        K = Cv;
        if      (row < 768)  src = wk  + (size_t)row * Cv;
        else if (row < 1536) src = wv  + (size_t)(row - 768) * Cv;
        else if (row < 2304) src = wr  + (size_t)(row - 1536) * Cv;
        else if (row < 3072) src = wo  + (size_t)(row - 2304) * Cv;
        else if (row < 6144) src = wkf + (size_t)(row - 3072) * Cv;
        else                 src = wrf + (size_t)(row - 6144) * Cv;
        dr = dstA + (size_t)row * Cv;
        sp = sWA + row;
    } else {
        K = Hv;
        int r2 = row - 6912;
        src = wvf + (size_t)r2 * Hv;
        dr = dstV + (size_t)r2 * Hv;
        sp = sWV + r2;
    }
    float am = 0.f;
    for (int j = threadIdx.x; j < K; j += 256) am = fmaxf(am, fabsf(src[j]));
#pragma unroll
    for (int off = 32; off > 0; off >>= 1) am = fmaxf(am, __shfl_xor(am, off));
    int wid = threadIdx.x >> 6;
    if ((threadIdx.x & 63) == 0) sh[wid] = am;
    __syncthreads();
    am = fmaxf(fmaxf(sh[0], sh[1]), fmaxf(sh[2], sh[3]));
    am = fmaxf(am, 1e-20f);
    float inv = 127.f / am;
    if (threadIdx.x == 0) *sp = am * (1.f / 127.f);
    for (int j = threadIdx.x; j < K; j += 256) dr[j] = (i8)(int)rintf(src[j] * inv);
}

// ---------------- y' (bf16, stride KVS) -> per-row i8 + scale ----------------
__global__ __launch_bounds__(256) void quant_y(const u16* __restrict__ kvs,
    i8* __restrict__ y8, float* __restrict__ sY)
{
    __shared__ float sh[4];
    int row = blockIdx.x;
    const u16* yr = kvs + (size_t)row * KVS;
    float v[3], am = 0.f;
#pragma unroll
    for (int i = 0; i < 3; i++) {
        v[i] = b2f(yr[threadIdx.x + 256 * i]);
        am = fmaxf(am, fabsf(v[i]));
    }
#pragma unroll
    for (int off = 32; off > 0; off >>= 1) am = fmaxf(am, __shfl_xor(am, off));
    int wid = threadIdx.x >> 6;
    if ((threadIdx.x & 63) == 0) sh[wid] = am;
    __syncthreads();
    am = fmaxf(fmaxf(sh[0], sh[1]), fmaxf(sh[2], sh[3]));
    am = fmaxf(am, 1e-20f);
    float inv = 127.f / am;
    if (threadIdx.x == 0) sY[row] = am * (1.f / 127.f);
    i8* orow = y8 + (size_t)row * Cv;
#pragma unroll
    for (int i = 0; i < 3; i++)
        orow[threadIdx.x + 256 * i] = (i8)(int)rintf(v[i] * inv);
}

// ---------------- requant kf: group scales -> single per-row scale (in place) -------
__global__ __launch_bounds__(192) void requant_kf(i8* __restrict__ kf,
    const float* __restrict__ sG, float* __restrict__ sKf)
{
    int tid = threadIdx.x;
    int row = blockIdx.x * 4 + tid / 48;
    int t = tid % 48;
    const float* sgr = sG + (size_t)row * NG;
    float am = 0.f;
#pragma unroll
    for (int g = 0; g < NG; g++) am = fmaxf(am, sgr[g]);
    if (t == 0) sKf[row] = am;
    float iam = 1.f / am;
    i8* kr = kf + (size_t)row * Hv;
#pragma unroll
    for (int p = 0; p < 4; p++) {
        int off = p * 768 + t * 16;
        float f = sgr[12 * p + (t >> 2)] * iam;
        i4v v = *(const i4v*)(kr + off);
        i4v o;
#pragma unroll
        for (int wq = 0; wq < 4; wq++) {
            unsigned r = 0;
#pragma unroll
            for (int b = 0; b < 4; b++) {
                int q = (int)(i8)((v[wq] >> (8 * b)) & 0xff);
                r |= ((unsigned)(unsigned char)(i8)(int)rintf((float)q * f)) << (8 * b);
            }
            o[wq] = (int)r;
        }
        *(i4v*)(kr + off) = o;
    }
}

// ---------------- int8 MFMA GEMM, 128x128 / 3 blocks/CU (round-10 proven) ----------
// EPI 0: bf16 out, sigmoid col>=sigoff (kvs)
// EPI 3: f32 out = b2f(x1b) + b2f(gate)*r (FFN down; e0=x1 bf16, e1=gate bf16)
// EPI 4: bf16 out = x + r (Wo; e0 = x fp32)
// EPI 6: FFN up+gate: cols<sigoff -> relu^2 group-quant i8 + sG; else sigmoid bf16
template<int EPI>
__global__ __launch_bounds__(256, 3) void gemm128q(const i8* __restrict__ A,
    const i8* __restrict__ W, void* __restrict__ outv, void* __restrict__ out2,
    int K, int lda, int ldw, int ldc, int ldc2, int ny, int sigoff,
    const float* __restrict__ sA, const float* __restrict__ sW,
    const void* __restrict__ e0, const u16* __restrict__ e1, float* __restrict__ sG)
{
    __shared__ i8 lds[3][2][8192];             // [buf][A/B][128*64]
    const int tid = threadIdx.x;
    const int wv = tid >> 6, l = tid & 63;
    const int nb = (int)gridDim.x, bid = (int)blockIdx.x;
    const int q = nb >> 3;
    const int sw = (bid & 7) * q + (bid >> 3);
    const int bm = (sw / ny) * 128, bn = (sw % ny) * 128;
    const int wr = wv >> 1, wc = wv & 1;
    const int row0 = wv * 32 + (l >> 2);
    const int scol = ((l & 3) ^ ((l >> 3) & 3)) << 4;
    const i8* srcA = A + (size_t)(bm + row0) * lda + scol;
    const i8* srcB = W + (size_t)(bn + row0) * ldw + scol;
#define STG(buf, kt) { \
    const size_t kc = (size_t)(kt) * 64; \
    GLOAD_LDS(srcA + kc,                    &lds[buf][0][wv * 2048]); \
    GLOAD_LDS(srcA + kc + (size_t)16 * lda, &lds[buf][0][wv * 2048 + 1024]); \
    GLOAD_LDS(srcB + kc,                    &lds[buf][1][wv * 2048]); \
    GLOAD_LDS(srcB + kc + (size_t)16 * ldw, &lds[buf][1][wv * 2048 + 1024]); }
    const int swz = ((l >> 4) ^ ((l >> 1) & 3)) << 4;
    const int ab  = (wr * 64 + (l & 15)) * 64 + swz;
    const int bb  = (wc * 64 + (l & 15)) * 64 + swz;
#define RD(pbuf) { \
    _Pragma("unroll") \
    for (int i = 0; i < 4; i++) { \
        a4[i] = *(const i4v*)&lds[pbuf][0][ab + i * 1024]; \
        b4[i] = *(const i4v*)&lds[pbuf][1][bb + i * 1024]; } }
#define MF() { \
    __builtin_amdgcn_s_setprio(1); \
    _Pragma("unroll") \
    for (int mm = 0; mm < 4; mm++) \
        _Pragma("unroll") \
        for (int nn = 0; nn < 4; nn++) \
            acc[mm][nn] = __builtin_amdgcn_mfma_i32_16x16x64_i8( \
                a4[mm], b4[nn], acc[mm][nn], 0, 0, 0); \
    __builtin_amdgcn_s_setprio(0); }

    i4v acc[4][4] = {};
    const int NKT = K >> 6;
    STG(0, 0); STG(1, 1);
    VM4();
    BAR();
    int cur = 0;
    for (int t = 0; t < NKT; ++t) {
        i4v a4[4], b4[4];
        RD(cur);
        const int n2 = cur >= 1 ? cur - 1 : 2;
        if (t + 2 < NKT) STG(n2, t + 2);
        MF();
        if (t + 2 < NKT)      VM4();
        else if (t + 1 < NKT) VM0();
        BAR();
        cur = cur >= 2 ? 0 : cur + 1;
    }
#undef STG
#undef RD
#undef MF
    // epilogue: C row=(lane>>4)*4+i, col=lane&15 per 16x16 fragment
    const int r0 = bm + wr * 64 + ((l >> 4) << 2);
    const int c0 = bn + wc * 64 + (l & 15);
    float sw4[4];
#pragma unroll
    for (int nf = 0; nf < 4; nf++) sw4[nf] = sW[c0 + nf * 16];
    if (EPI == 6 && bn < sigoff) {
        // kf block: relu^2, per-(row, 64-col-group) quantize to i8
        const int g = (bn + wc * 64) >> 6;
        i8* kf8 = (i8*)outv;
#pragma unroll
        for (int mf = 0; mf < 4; mf++)
#pragma unroll
            for (int i = 0; i < 4; i++) {
                const int row = r0 + mf * 16 + i;
                const float sar = sA[row];
                float v[4], amx = 0.f;
#pragma unroll
                for (int nf = 0; nf < 4; nf++) {
                    float r = (float)acc[mf][nf][i] * sar * sw4[nf];
                    r = fmaxf(r, 0.f);
                    v[nf] = r * r;
                    amx = fmaxf(amx, v[nf]);
                }
#pragma unroll
                for (int off = 8; off >= 1; off >>= 1)
                    amx = fmaxf(amx, __shfl_xor(amx, off));   // max over 16 col-lanes
                amx = fmaxf(amx, 1e-20f);
                float inv = 127.f / amx;
#pragma unroll
                for (int nf = 0; nf < 4; nf++)
                    kf8[(size_t)row * ldc + (c0 + nf * 16)] = (i8)(int)rintf(v[nf] * inv);
                if ((l & 15) == 0) sG[(size_t)row * NG + g] = amx * (1.f / 127.f);
            }
        return;
    }
#pragma unroll
    for (int mf = 0; mf < 4; mf++)
#pragma unroll
        for (int i = 0; i < 4; i++) {
            const int row = r0 + mf * 16 + i;
            const float sar = sA[row];
#pragma unroll
            for (int nf = 0; nf < 4; nf++) {
                const int col = c0 + nf * 16;
                float r = (float)acc[mf][nf][i] * sar * sw4[nf];
                if (EPI == 0) {
                    if (col >= sigoff) r = 1.f / (1.f + __expf(-r));
                    ((u16*)outv)[(size_t)row * ldc + col] = f2b(r);
                } else if (EPI == 3) {
                    size_t o = (size_t)row * ldc + col;
                    ((float*)outv)[o] = fmaf(b2f(e1[(size_t)row * Cv + col]), r,
                                             b2f(((const u16*)e0)[o]));
                } else if (EPI == 4) {
                    size_t o = (size_t)row * ldc + col;
                    ((u16*)outv)[o] = f2b(((const float*)e0)[o] + r);
                } else if (EPI == 6) {
                    float sg = 1.f / (1.f + __expf(-r));
                    ((u16*)out2)[(size_t)row * ldc2 + (col - sigoff)] = f2b(sg);
                }
            }
        }
}

// ---------------- WKV helpers ----------------
__device__ __forceinline__ void wkv_step(float& a, float& b, float& m,
                                         float w, float kt, float vt)
{
    float mm = fmaxf(m + w, kt);
    float e1 = __expf(m + w - mm);
    float e2 = __expf(kt - mm);
    a = e1 * a + e2 * vt;
    b = e1 * b + e2;
    m = mm;
}
__device__ __forceinline__ void wkv_merge(float& a, float& b, float& m,
                                          float shift, float a2, float b2, float m2)
{
    float ms = m + shift;
    float mm = fmaxf(ms, m2);
    float e1 = __expf(ms - mm);
    float e2 = __expf(m2 - mm);
    a = e1 * a + e2 * a2;
    b = e1 * b + e2 * b2;
    m = mm;
}

// ---------------- WKV pass 1: per-chunk summaries, direction-split ----------------
__global__ __launch_bounds__(256) void wkv_pass1(const u16* __restrict__ kvs,
    const float* __restrict__ decay, float* __restrict__ sums)
{
    int e = blockIdx.x * 256 + threadIdx.x;
    const int PN = NCHK * BC;
    int dir = e / PN, r = e % PN;
    int idx = r % BC, ci = r / BC;
    int b = idx / Cv, c = idx % Cv;
    float w = decay[c] * (1.f / (float)Tv);
    size_t base = ((size_t)b * Tv + (size_t)ci * Lc) * KVS + c;
    const size_t P = (size_t)NCHK * BC;
    size_t so = (size_t)ci * BC + idx;
    float a = 0.f, bb = 0.f, m = -1e38f;
    if (dir == 0) {
        for (int t = 0; t < Lc; t++) {
            size_t off = base + (size_t)t * KVS;
            wkv_step(a, bb, m, w, b2f(kvs[off]), b2f(kvs[off + 768]));
        }
        sums[0 * P + so] = a; sums[1 * P + so] = bb; sums[2 * P + so] = m;
    } else {
        for (int t = Lc - 1; t >= 0; t--) {
            size_t off = base + (size_t)t * KVS;
            wkv_step(a, bb, m, w, b2f(kvs[off]), b2f(kvs[off + 768]));
        }
        sums[3 * P + so] = a; sums[4 * P + so] = bb; sums[5 * P + so] = m;
    }
}

// ---------------- WKV pass 2: scan chunk summaries, direction-split ----------------
__global__ __launch_bounds__(256) void wkv_pass2(const float* __restrict__ decay,
    const float* __restrict__ sums, float* __restrict__ chks)
{
    int e = blockIdx.x * 256 + threadIdx.x;
    int dir = e / BC, idx = e % BC;
    int c = idx % Cv;
    float shift = decay[c] * (1.f / (float)Tv) * (float)Lc;
    const size_t P = (size_t)NCHK * BC;
    float a = 0.f, bb = 0.f, m = -1e38f;
    if (dir == 0) {
        for (int ci = 0; ci < NCHK; ci++) {
            size_t so = (size_t)ci * BC + idx;
            chks[0 * P + so] = a; chks[1 * P + so] = bb; chks[2 * P + so] = m;
            wkv_merge(a, bb, m, shift, sums[0 * P + so], sums[1 * P + so], sums[2 * P + so]);
        }
    } else {
        for (int ci = NCHK - 1; ci >= 0; ci--) {
            size_t so = (size_t)ci * BC + idx;
            chks[3 * P + so] = a; chks[4 * P + so] = bb; chks[5 * P + so] = m;
            wkv_merge(a, bb, m, shift, sums[3 * P + so], sums[4 * P + so], sums[5 * P + so]);
        }
    }
}

// ---------------- WKV pass 3: per-chunk combine, writes y*sr over k slot ----------------
__global__ __launch_bounds__(256) void wkv_pass3(u16* __restrict__ kvs,
    const float* __restrict__ decay, const float* __restrict__ first,
    const float* __restrict__ chks)
{
    int e = blockIdx.x * 256 + threadIdx.x;
    int idx = e % BC, ci = e / BC;
    int b = idx / Cv, c = idx % Cv;
    float w = decay[c] * (1.f / (float)Tv);
    float u = first[c] * (1.f / (float)Tv);
    const size_t P = (size_t)NCHK * BC;
    size_t so = (size_t)ci * BC + idx;
    size_t base = ((size_t)b * Tv + (size_t)ci * Lc) * KVS + c;
    float sa = chks[3 * P + so], sb2 = chks[4 * P + so], sm = chks[5 * P + so];
    float Ba[SI], Bb[SI], Bm[SI];
#pragma unroll
    for (int si = SI - 1; si >= 0; si--) {
        Ba[si] = sa; Bb[si] = sb2; Bm[si] = sm;
        for (int j = 15; j >= 0; j--) {
            size_t off = base + (size_t)(si * 16 + j) * KVS;
            wkv_step(sa, sb2, sm, w, b2f(kvs[off]), b2f(kvs[off + 768]));
        }
    }
    float fa = chks[0 * P + so], fb2 = chks[1 * P + so], fm = chks[2 * P + so];
#pragma unroll
    for (int si = 0; si < SI; si++) {
        float lk[16], lv[16], la[16], lb[16], lm[16];
        float ta = Ba[si], tb = Bb[si], tm = Bm[si];
#pragma unroll
        for (int j = 15; j >= 0; j--) {
            size_t off = base + (size_t)(si * 16 + j) * KVS;
            lk[j] = b2f(kvs[off]); lv[j] = b2f(kvs[off + 768]);
            la[j] = ta; lb[j] = tb; lm[j] = tm;
            wkv_step(ta, tb, tm, w, lk[j], lv[j]);
        }
#pragma unroll
        for (int j = 0; j < 16; j++) {
            float kk = lk[j] + u;
            float M  = fmaxf(fmaxf(fm, lm[j]), kk);
            float ef = __expf(fm - M);
            float eb = __expf(lm[j] - M);
            float ec = __expf(kk - M);
            float num = ef * fa + eb * la[j] + ec * lv[j];
            float den = ef * fb2 + eb * lb[j] + ec;
            size_t off = base + (size_t)(si * 16 + j) * KVS;
            kvs[off] = f2b(b2f(kvs[off + 1536]) * (num / den));  // y' = sr * y
            wkv_step(fa, fb2, fm, w, lk[j], lv[j]);
        }
    }
}

__global__ __launch_bounds__(256) void fill_signal(float* __restrict__ out, int n, float val)
{
    int i = blockIdx.x * 256 + threadIdx.x;
    if (i < n) out[i] = val;
}

extern "C" void kernel_launch(void* const* d_in, const int* in_sizes, int n_in,
                              void* d_out, int out_size, void* d_ws, size_t ws_size,
                              hipStream_t stream)
{
    const float* x     = (const float*)d_in[0];
    const float* ln1_w = (const float*)d_in[1];
    const float* ln1_b = (const float*)d_in[2];
    const float* ln2_w = (const float*)d_in[3];
    const float* ln2_b = (const float*)d_in[4];
    const float* decay = (const float*)d_in[5];
    const float* first = (const float*)d_in[6];
    const float* Wk_a  = (const float*)d_in[7];
    const float* Wv_a  = (const float*)d_in[8];
    const float* Wr_a  = (const float*)d_in[9];
    const float* Wo_a  = (const float*)d_in[10];
    const float* Wk_f  = (const float*)d_in[11];
    const float* Wv_f  = (const float*)d_in[12];
    const float* Wr_f  = (const float*)d_in[13];
    float* out = (float*)d_out;

    const size_t NCe = (size_t)BT * Cv;        // 12,582,912
    const size_t SUM = (size_t)6 * NCHK * BC;
    const int    WR  = 6912;                   // stacked K=768 weight rows

    char* p = (char*)d_ws;
    i8*  h8    = (i8*)p;            p += NCe;                 // h1 / y8 / h2 (serial reuse)
    u16* kvs   = (u16*)p;           p += 3 * NCe * 2;         // k|v|sr bf16 (stride 2304)
    u16* x1b   = (u16*)p;           p += NCe * 2;             // x after attention (bf16)
    i8*  wAll  = (i8*)p;            p += (size_t)WR * Cv;     // stacked K=768 weights i8
    i8*  wVf8  = (i8*)p;            p += (size_t)Cv * Hv;     // Wv_f i8
    float* sums = (float*)p;        p += SUM * 4;
    float* chks = (float*)p;        p += SUM * 4;
    float* sAct = (float*)p;        p += (size_t)BT * 4;      // h / h2 row scales
    float* sY   = (float*)p;        p += (size_t)BT * 4;      // y' row scales
    float* sG   = (float*)p;        p += (size_t)BT * NG * 4; // kf group scales (3.1 MB)
    float* sKf  = (float*)p;        p += (size_t)BT * 4;      // kf per-row scales
    float* sWall = (float*)p;       p += (size_t)WR * 4;
    float* sWv  = (float*)p;        p += (size_t)Cv * 4;
    size_t need = (size_t)(p - (char*)d_ws);

    if (ws_size < need) {
        fill_signal<<<(int)((NCe + 255) / 256), 256, 0, stream>>>(out, (int)NCe, (float)(ws_size >> 20));
        return;
    }

    // overlays into dead kvs region (after quant_y):
    u16* gate = kvs;                           // BT x 768 bf16   (25.2 MB)
    i8*  kf_8 = (i8*)(kvs + NCe);              // BT x 3072 i8    (50.3 MB)

    dim3 blk(256);
    // all-weights quantization, one dispatch (7680 rows)
    quant_wAll<<<WR + Cv, blk, 0, stream>>>(Wk_a, Wv_a, Wr_a, Wo_a, Wk_f, Wr_f, Wv_f,
                                            wAll, sWall, wVf8, sWv);

    // 1. h = LN1(x fp32) -> i8 + row scales
    ln_q8<0><<<BT, blk, 0, stream>>>(x, ln1_w, ln1_b, h8, sAct);
    // 2. fused [k|v|sr] = h @ [Wk;Wv;Wr]^T, sigmoid cols >= 1536. grid 2304 = 3.0 rounds
    gemm128q<0><<<dim3((BT / 128) * (KVS / 128)), blk, 0, stream>>>(
        h8, wAll, kvs, nullptr, Cv, Cv, Cv, KVS, 0, KVS / 128, 1536,
        sAct, sWall, nullptr, nullptr, nullptr);
    // 3. bidirectional WKV; y' = sr*y written over k slot
    wkv_pass1<<<(2 * BC * NCHK) / 256, blk, 0, stream>>>(kvs, decay, sums);
    wkv_pass2<<<(2 * BC) / 256, blk, 0, stream>>>(decay, sums, chks);
    wkv_pass3<<<(BC * NCHK) / 256, blk, 0, stream>>>(kvs, decay, first, chks);
    // 4. y' -> i8; x1b = bf16(x + y8 @ Wo^T). grid 768 = 1.0 round
    quant_y<<<BT, blk, 0, stream>>>(kvs, h8, sY);
    gemm128q<4><<<dim3((BT / 128) * (Cv / 128)), blk, 0, stream>>>(
        h8, wAll + (size_t)2304 * Cv, x1b, nullptr, Cv, Cv, Cv, Cv, 0, Cv / 128, 0,
        sY, sWall + 2304, x, nullptr, nullptr);
    // 5. h2 = LN2(x1b bf16) -> i8 + row scales
    ln_q8<1><<<BT, blk, 0, stream>>>(x1b, ln2_w, ln2_b, h8, sAct);
    // 6. FFN up+gate, unchunked: [kf_i8+sG | gate] = h2 @ [Wk_f;Wr_f]^T. grid 3840
    gemm128q<6><<<dim3((BT / 128) * ((Hv + Cv) / 128)), blk, 0, stream>>>(
        h8, wAll + (size_t)3072 * Cv, kf_8, gate, Cv, Cv, Cv, Hv, Cv,
        (Hv + Cv) / 128, Hv, sAct, sWall + 3072, nullptr, nullptr, sG);
    // 6b. requant kf: group scales -> per-row scale (in place)
    requant_kf<<<BT / 4, dim3(192), 0, stream>>>(kf_8, sG, sKf);
    // 7. FFN down, pure-int K-loop. out = x1b + gate * r. grid 768 = 1.0 round
    gemm128q<3><<<dim3((BT / 128) * (Cv / 128)), blk, 0, stream>>>(
        kf_8, wVf8, out, nullptr, Hv, Hv, Hv, Cv, 0, Cv / 128, 0,
        sKf, sWv, x1b, gate, nullptr);
}